// Round 3
// baseline (2120.369 us; speedup 1.0000x reference)
//
#include <hip/hip_runtime.h>

#define NN 100000
#define NE 3200000
#define DIN 512
#define DHID 256
#define DOUT 64
#define KPROP 10
#define NB ((NN + 127) >> 7)   // 782 dst-buckets of 128 nodes

typedef _Float16 f16;
typedef _Float16 f16x8 __attribute__((ext_vector_type(8)));
typedef _Float16 f16x4 __attribute__((ext_vector_type(4)));
typedef float f32x4 __attribute__((ext_vector_type(4)));

// ---------------- edge-index layout probe ----------------
__global__ void detect_i64(const int* __restrict__ ei, int* __restrict__ flag) {
  if (blockIdx.x == 0 && threadIdx.x == 0) {
    int z = 1;
    for (int i = 0; i < 512; i++) if (ei[2*i + 1] != 0) { z = 0; break; }
    *flag = z;
  }
}

__device__ __forceinline__ int edge_at(const int* __restrict__ ei, int row, int e, int is64) {
  size_t base = (size_t)row * NE + (size_t)e;
  return is64 ? ei[base * 2] : ei[base];
}

// ---------------- degree count ----------------
__global__ void zero_cnt(int* __restrict__ cnt) {
  int g = blockIdx.x * blockDim.x + threadIdx.x;
  if (g < NN) cnt[g] = 0;
}

__global__ void count_deg(const int* __restrict__ ei, const int* __restrict__ flag,
                          int* __restrict__ cnt) {
  int g = blockIdx.x * blockDim.x + threadIdx.x;
  if (g < NE) {
    int d = edge_at(ei, 1, g, *flag);
    atomicAdd(&cnt[d], 1);
  }
}

// ---------------- exclusive scan over cnt ----------------
__global__ void scan1(const int* __restrict__ cnt, int* __restrict__ rs,
                      int* __restrict__ bsum) {
  __shared__ int tmp[1024];
  int t = threadIdx.x;
  int g = blockIdx.x * 1024 + t;
  int v = (g < NN) ? cnt[g] : 0;
  tmp[t] = v;
  __syncthreads();
  for (int off = 1; off < 1024; off <<= 1) {
    int y = (t >= off) ? tmp[t - off] : 0;
    __syncthreads();
    tmp[t] += y;
    __syncthreads();
  }
  if (g < NN) rs[g] = tmp[t] - v;           // exclusive
  if (t == 1023) bsum[blockIdx.x] = tmp[t]; // block total
}

__global__ void scan2(int* __restrict__ bsum, int nb) {
  if (blockIdx.x == 0 && threadIdx.x == 0) {
    int s = 0;
    for (int i = 0; i < nb; i++) { int v = bsum[i]; bsum[i] = s; s += v; }
  }
}

__global__ void scan3_and_dis(int* __restrict__ rs, const int* __restrict__ bsum,
                              int* __restrict__ cursor, const int* __restrict__ cnt,
                              float* __restrict__ dis, int* __restrict__ bcur) {
  int g = blockIdx.x * blockDim.x + threadIdx.x;
  if (g < NN) {
    int v = rs[g] + bsum[g >> 10];
    rs[g] = v;
    cursor[g] = v;
    dis[g] = rsqrtf((float)(cnt[g] + 1)); // +1 self-loop
    if ((g & 127) == 0) bcur[g >> 7] = v; // bucket base = rs at bucket start
  }
}

// ---------------- CSR build, pass 1: bucket scatter ----------------
// Scatter {src,dst} into the dst-bucket's CSR region. ~782 active write
// windows -> lines fill before eviction (vs. 3.2M random 4B writes before).
__global__ void pass1_bucket(const int* __restrict__ ei, const int* __restrict__ flag,
                             int* __restrict__ bcur, int2* __restrict__ tmp) {
  int g = blockIdx.x * blockDim.x + threadIdx.x;
  if (g < NE) {
    int is64 = *flag;
    int s = edge_at(ei, 0, g, is64);
    int d = edge_at(ei, 1, g, is64);
    int p = atomicAdd(&bcur[d >> 7], 1);
    tmp[p] = make_int2(s, d);
  }
}

// ---------------- CSR build, pass 2: in-bucket placement ----------------
// One block per bucket; read/write confined to the bucket's ~25KB window.
__global__ __launch_bounds__(256) void pass2_place(
    const int2* __restrict__ tmp, int* __restrict__ cursor,
    const int* __restrict__ rs, int* __restrict__ col) {
  int b = blockIdx.x;
  int lo = rs[b << 7];
  int hi = (b == NB - 1) ? NE : rs[(b + 1) << 7];
  for (int i = lo + threadIdx.x; i < hi; i += 256) {
    int2 e = tmp[i];
    int p = atomicAdd(&cursor[e.y], 1);
    col[p] = e.x;
  }
}

// ---------------- weight transpose + fp16 convert ----------------
__global__ void cvt_weights(const float* __restrict__ W1, const float* __restrict__ W2,
                            f16* __restrict__ W1t, f16* __restrict__ W2t) {
  int g = blockIdx.x * 256 + threadIdx.x;
  if (g < DIN * DHID) {
    int k = g >> 8, n = g & 255;
    W1t[(size_t)n * DIN + k] = (f16)W1[g];
  }
  if (g < DHID * DOUT) {
    int k = g >> 6, n = g & 63;
    W2t[(size_t)n * DHID + k] = (f16)W2[g];
  }
}

// ---------------- fused MLP via f16 MFMA ----------------
__global__ __launch_bounds__(256) void mlp_mfma(
    const float* __restrict__ x, const f16* __restrict__ W1t,
    const float* __restrict__ b1, const f16* __restrict__ W2t,
    const float* __restrict__ b2, const float* __restrict__ temp,
    f16* __restrict__ h, float* __restrict__ out)
{
  __shared__ f16 xs[64][136];
  __shared__ f16 h1s[64][264];
  int t = threadIdx.x;
  int lane = t & 63;
  int w = t >> 6;
  int n0 = blockIdx.x * 64;
  int r15 = lane & 15;
  int g4 = lane >> 4;
  int nbase = w * 64;

  f32x4 acc[4][4];
  #pragma unroll
  for (int nt = 0; nt < 4; nt++) {
    float bv = b1[nbase + nt * 16 + r15];
    #pragma unroll
    for (int mt = 0; mt < 4; mt++) acc[mt][nt] = (f32x4){bv, bv, bv, bv};
  }

  for (int k0 = 0; k0 < DIN; k0 += 128) {
    if (k0) __syncthreads();
    #pragma unroll
    for (int it = 0; it < 8; it++) {
      int m = t + it * 256;
      int row = m >> 5, c4 = m & 31;
      int gr = n0 + row;
      float4 v = (gr < NN) ? *(const float4*)&x[(size_t)gr * DIN + k0 + c4 * 4]
                           : make_float4(0.f, 0.f, 0.f, 0.f);
      f16x4 hv = { (f16)v.x, (f16)v.y, (f16)v.z, (f16)v.w };
      *(f16x4*)&xs[row][c4 * 4] = hv;
    }
    __syncthreads();
    #pragma unroll
    for (int ks = 0; ks < 4; ks++) {
      int kk = ks * 32 + g4 * 8;
      f16x8 a[4], b[4];
      #pragma unroll
      for (int mt = 0; mt < 4; mt++)
        a[mt] = *(const f16x8*)&xs[mt * 16 + r15][kk];
      #pragma unroll
      for (int nt = 0; nt < 4; nt++)
        b[nt] = *(const f16x8*)&W1t[(size_t)(nbase + nt * 16 + r15) * DIN + k0 + kk];
      #pragma unroll
      for (int mt = 0; mt < 4; mt++)
        #pragma unroll
        for (int nt = 0; nt < 4; nt++)
          acc[mt][nt] = __builtin_amdgcn_mfma_f32_16x16x32_f16(a[mt], b[nt], acc[mt][nt], 0, 0, 0);
    }
  }
  #pragma unroll
  for (int mt = 0; mt < 4; mt++)
    #pragma unroll
    for (int nt = 0; nt < 4; nt++)
      #pragma unroll
      for (int r = 0; r < 4; r++) {
        float v = fmaxf(acc[mt][nt][r], 0.f);
        h1s[mt * 16 + g4 * 4 + r][nbase + nt * 16 + r15] = (f16)v;
      }
  __syncthreads();

  f32x4 acc2[4];
  #pragma unroll
  for (int nt = 0; nt < 4; nt++) {
    float bv = b2[nt * 16 + r15];
    acc2[nt] = (f32x4){bv, bv, bv, bv};
  }
  #pragma unroll
  for (int ks = 0; ks < 8; ks++) {
    int kk = ks * 32 + g4 * 8;
    f16x8 a2 = *(const f16x8*)&h1s[w * 16 + r15][kk];
    #pragma unroll
    for (int nt = 0; nt < 4; nt++) {
      f16x8 bf = *(const f16x8*)&W2t[(size_t)(nt * 16 + r15) * DHID + kk];
      acc2[nt] = __builtin_amdgcn_mfma_f32_16x16x32_f16(a2, bf, acc2[nt], 0, 0, 0);
    }
  }
  float t0 = temp[0];
  #pragma unroll
  for (int nt = 0; nt < 4; nt++)
    #pragma unroll
    for (int r = 0; r < 4; r++) {
      int node = n0 + w * 16 + g4 * 4 + r;
      if (node < NN) {
        int colv = nt * 16 + r15;
        float v = acc2[nt][r];
        h[(size_t)node * DOUT + colv] = (f16)v;
        out[(size_t)node * DOUT + colv] = t0 * v;
      }
    }
}

// ---------------- propagation: hk_next = A_hat hk; out += temp[k]*hk_next --
// One wave per node, lane = feature. norm computed on the fly from the hot
// 400KB dis table (broadcast loads). acc = dd*h_self + sum dis[c]*h_c; then
// scaled once by dd.
__global__ __launch_bounds__(256) void prop_step(
    const f16* __restrict__ hk, f16* __restrict__ hkn, float* __restrict__ out,
    const int* __restrict__ rs, const int* __restrict__ cnt,
    const int* __restrict__ col, const float* __restrict__ dis,
    const float* __restrict__ temp, int kidx)
{
  int w = blockIdx.x * 4 + (threadIdx.x >> 6);
  int lane = threadIdx.x & 63;
  if (w >= NN) return;
  float dd = dis[w];
  size_t rowoff = (size_t)w * DOUT + lane;
  float a0 = dd * (float)hk[rowoff];  // self-loop (final scale by dd below)
  float a1 = 0.f;
  int beg = rs[w], n = cnt[w];
  const int* cp = col + beg;
  int e = 0;
  for (; e + 8 <= n; e += 8) {
    int c0 = cp[e+0], c1 = cp[e+1], c2 = cp[e+2], c3 = cp[e+3];
    int c4 = cp[e+4], c5 = cp[e+5], c6 = cp[e+6], c7 = cp[e+7];
    float d0 = dis[c0], d1 = dis[c1], d2 = dis[c2], d3 = dis[c3];
    float d4 = dis[c4], d5 = dis[c5], d6 = dis[c6], d7 = dis[c7];
    float h0 = (float)hk[(size_t)c0 * DOUT + lane];
    float h1 = (float)hk[(size_t)c1 * DOUT + lane];
    float h2 = (float)hk[(size_t)c2 * DOUT + lane];
    float h3 = (float)hk[(size_t)c3 * DOUT + lane];
    float h4 = (float)hk[(size_t)c4 * DOUT + lane];
    float h5 = (float)hk[(size_t)c5 * DOUT + lane];
    float h6 = (float)hk[(size_t)c6 * DOUT + lane];
    float h7 = (float)hk[(size_t)c7 * DOUT + lane];
    a0 = fmaf(d0, h0, a0); a1 = fmaf(d1, h1, a1);
    a0 = fmaf(d2, h2, a0); a1 = fmaf(d3, h3, a1);
    a0 = fmaf(d4, h4, a0); a1 = fmaf(d5, h5, a1);
    a0 = fmaf(d6, h6, a0); a1 = fmaf(d7, h7, a1);
  }
  for (; e < n; ++e) {
    int c = cp[e];
    a0 = fmaf(dis[c], (float)hk[(size_t)c * DOUT + lane], a0);
  }
  float a = dd * (a0 + a1);
  hkn[rowoff] = (f16)a;
  out[rowoff] += temp[kidx] * a;
}

// ---------------- launch ----------------
extern "C" void kernel_launch(void* const* d_in, const int* in_sizes, int n_in,
                              void* d_out, int out_size, void* d_ws, size_t ws_size,
                              hipStream_t stream) {
  const float* x    = (const float*)d_in[0];
  const int*   ei   = (const int*)d_in[1];
  const float* W1   = (const float*)d_in[2];
  const float* b1   = (const float*)d_in[3];
  const float* W2   = (const float*)d_in[4];
  const float* b2   = (const float*)d_in[5];
  const float* temp = (const float*)d_in[6];
  float* out = (float*)d_out;

  char* wsb = (char*)d_ws;
  size_t off = 0;
  auto carve = [&](size_t bytes) -> void* {
    void* p = wsb + off;
    off = (off + bytes + 255) & ~(size_t)255;
    return p;
  };
  int*   cnt    = (int*)carve((size_t)NN * 4);
  int*   rs     = (int*)carve((size_t)NN * 4);
  int*   cursor = (int*)carve((size_t)NN * 4);
  int*   bsum   = (int*)carve(128 * 4);
  int*   flag   = (int*)carve(256);
  float* dis    = (float*)carve((size_t)NN * 4);
  int*   bcur   = (int*)carve((size_t)NB * 4);
  int2*  tmp    = (int2*)carve((size_t)NE * 8);  // 25.6 MB
  int*   col    = (int*)carve((size_t)NE * 4);   // 12.8 MB
  f16*   W1t    = (f16*)carve((size_t)DHID * DIN * 2);
  f16*   W2t    = (f16*)carve((size_t)DOUT * DHID * 2);
  f16*   hk_a   = (f16*)carve((size_t)NN * DOUT * 2);
  f16*   hk_b   = (f16*)carve((size_t)NN * DOUT * 2);
  if (off > ws_size) return; // ~67 MB needed

  detect_i64<<<1, 64, 0, stream>>>(ei, flag);
  zero_cnt<<<(NN + 255) / 256, 256, 0, stream>>>(cnt);
  count_deg<<<(NE + 255) / 256, 256, 0, stream>>>(ei, flag, cnt);
  scan1<<<(NN + 1023) / 1024, 1024, 0, stream>>>(cnt, rs, bsum);
  scan2<<<1, 64, 0, stream>>>(bsum, (NN + 1023) / 1024);
  scan3_and_dis<<<(NN + 255) / 256, 256, 0, stream>>>(rs, bsum, cursor, cnt, dis, bcur);
  pass1_bucket<<<(NE + 255) / 256, 256, 0, stream>>>(ei, flag, bcur, tmp);
  pass2_place<<<NB, 256, 0, stream>>>(tmp, cursor, rs, col);

  cvt_weights<<<(DIN * DHID + 255) / 256, 256, 0, stream>>>(W1, W2, W1t, W2t);
  mlp_mfma<<<(NN + 63) / 64, 256, 0, stream>>>(x, W1t, b1, W2t, b2, temp, hk_a, out);

  const f16* cur = hk_a;
  f16* nxt = hk_b;
  for (int k = 1; k <= KPROP; k++) {
    prop_step<<<(NN + 3) / 4, 256, 0, stream>>>(cur, nxt, out, rs, cnt, col,
                                                dis, temp, k);
    const f16* t2 = nxt;
    nxt = (f16*)cur;
    cur = t2;
  }
}

// Round 4
// 1829.511 us; speedup vs baseline: 1.1590x; 1.1590x over previous
//
#include <hip/hip_runtime.h>

#define NN 100000
#define NE 3200000
#define DIN 512
#define DHID 256
#define DOUT 64
#define KPROP 10

typedef _Float16 f16;
typedef _Float16 f16x8 __attribute__((ext_vector_type(8)));
typedef _Float16 f16x4 __attribute__((ext_vector_type(4)));
typedef float f32x4 __attribute__((ext_vector_type(4)));

// ---------------- edge-index layout probe ----------------
__global__ void detect_i64(const int* __restrict__ ei, int* __restrict__ flag) {
  if (blockIdx.x == 0 && threadIdx.x == 0) {
    int z = 1;
    for (int i = 0; i < 512; i++) if (ei[2*i + 1] != 0) { z = 0; break; }
    *flag = z;
  }
}

__device__ __forceinline__ int edge_at(const int* __restrict__ ei, int row, int e, int is64) {
  size_t base = (size_t)row * NE + (size_t)e;
  return is64 ? ei[base * 2] : ei[base];
}

// ---------------- degree count ----------------
__global__ void zero_cnt(int* __restrict__ cnt) {
  int g = blockIdx.x * blockDim.x + threadIdx.x;
  if (g < NN) cnt[g] = 0;
}

// 3.2M atomics over 100k counters = 32/address: low contention (r3 lesson:
// contention scales with ops/ADDRESS — the 782-bucket variant was 440cyc/op).
__global__ void count_deg(const int* __restrict__ ei, const int* __restrict__ flag,
                          int* __restrict__ cnt) {
  int g = blockIdx.x * blockDim.x + threadIdx.x;
  if (g < NE) {
    int d = edge_at(ei, 1, g, *flag);
    atomicAdd(&cnt[d], 1);
  }
}

// ---------------- exclusive scan over cnt ----------------
__global__ void scan1(const int* __restrict__ cnt, int* __restrict__ rs,
                      int* __restrict__ bsum) {
  __shared__ int tmp[1024];
  int t = threadIdx.x;
  int g = blockIdx.x * 1024 + t;
  int v = (g < NN) ? cnt[g] : 0;
  tmp[t] = v;
  __syncthreads();
  for (int off = 1; off < 1024; off <<= 1) {
    int y = (t >= off) ? tmp[t - off] : 0;
    __syncthreads();
    tmp[t] += y;
    __syncthreads();
  }
  if (g < NN) rs[g] = tmp[t] - v;           // exclusive
  if (t == 1023) bsum[blockIdx.x] = tmp[t]; // block total
}

__global__ void scan2(int* __restrict__ bsum, int nb) {
  if (blockIdx.x == 0 && threadIdx.x == 0) {
    int s = 0;
    for (int i = 0; i < nb; i++) { int v = bsum[i]; bsum[i] = s; s += v; }
  }
}

__global__ void scan3_and_dis(int* __restrict__ rs, const int* __restrict__ bsum,
                              int* __restrict__ cursor, const int* __restrict__ cnt,
                              float* __restrict__ dis) {
  int g = blockIdx.x * blockDim.x + threadIdx.x;
  if (g < NN) {
    int v = rs[g] + bsum[g >> 10];
    rs[g] = v;
    cursor[g] = v;
    dis[g] = rsqrtf((float)(cnt[g] + 1)); // +1 self-loop
  }
}

// ---------------- CSR fill: per-node cursor, col only ----------------
__global__ void fill_csr(const int* __restrict__ ei, const int* __restrict__ flag,
                         int* __restrict__ cursor, int* __restrict__ col) {
  int g = blockIdx.x * blockDim.x + threadIdx.x;
  if (g < NE) {
    int is64 = *flag;
    int s = edge_at(ei, 0, g, is64);
    int d = edge_at(ei, 1, g, is64);
    int p = atomicAdd(&cursor[d], 1);
    col[p] = s;
  }
}

// ---------------- weight transpose + fp16 convert ----------------
__global__ void cvt_weights(const float* __restrict__ W1, const float* __restrict__ W2,
                            f16* __restrict__ W1t, f16* __restrict__ W2t) {
  int g = blockIdx.x * 256 + threadIdx.x;
  if (g < DIN * DHID) {
    int k = g >> 8, n = g & 255;
    W1t[(size_t)n * DIN + k] = (f16)W1[g];
  }
  if (g < DHID * DOUT) {
    int k = g >> 6, n = g & 63;
    W2t[(size_t)n * DHID + k] = (f16)W2[g];
  }
}

// ---------------- fused MLP via f16 MFMA ----------------
__global__ __launch_bounds__(256) void mlp_mfma(
    const float* __restrict__ x, const f16* __restrict__ W1t,
    const float* __restrict__ b1, const f16* __restrict__ W2t,
    const float* __restrict__ b2, const float* __restrict__ temp,
    f16* __restrict__ h, float* __restrict__ out)
{
  __shared__ f16 xs[64][136];
  __shared__ f16 h1s[64][264];
  int t = threadIdx.x;
  int lane = t & 63;
  int w = t >> 6;
  int n0 = blockIdx.x * 64;
  int r15 = lane & 15;
  int g4 = lane >> 4;
  int nbase = w * 64;

  f32x4 acc[4][4];
  #pragma unroll
  for (int nt = 0; nt < 4; nt++) {
    float bv = b1[nbase + nt * 16 + r15];
    #pragma unroll
    for (int mt = 0; mt < 4; mt++) acc[mt][nt] = (f32x4){bv, bv, bv, bv};
  }

  for (int k0 = 0; k0 < DIN; k0 += 128) {
    if (k0) __syncthreads();
    #pragma unroll
    for (int it = 0; it < 8; it++) {
      int m = t + it * 256;
      int row = m >> 5, c4 = m & 31;
      int gr = n0 + row;
      float4 v = (gr < NN) ? *(const float4*)&x[(size_t)gr * DIN + k0 + c4 * 4]
                           : make_float4(0.f, 0.f, 0.f, 0.f);
      f16x4 hv = { (f16)v.x, (f16)v.y, (f16)v.z, (f16)v.w };
      *(f16x4*)&xs[row][c4 * 4] = hv;
    }
    __syncthreads();
    #pragma unroll
    for (int ks = 0; ks < 4; ks++) {
      int kk = ks * 32 + g4 * 8;
      f16x8 a[4], b[4];
      #pragma unroll
      for (int mt = 0; mt < 4; mt++)
        a[mt] = *(const f16x8*)&xs[mt * 16 + r15][kk];
      #pragma unroll
      for (int nt = 0; nt < 4; nt++)
        b[nt] = *(const f16x8*)&W1t[(size_t)(nbase + nt * 16 + r15) * DIN + k0 + kk];
      #pragma unroll
      for (int mt = 0; mt < 4; mt++)
        #pragma unroll
        for (int nt = 0; nt < 4; nt++)
          acc[mt][nt] = __builtin_amdgcn_mfma_f32_16x16x32_f16(a[mt], b[nt], acc[mt][nt], 0, 0, 0);
    }
  }
  #pragma unroll
  for (int mt = 0; mt < 4; mt++)
    #pragma unroll
    for (int nt = 0; nt < 4; nt++)
      #pragma unroll
      for (int r = 0; r < 4; r++) {
        float v = fmaxf(acc[mt][nt][r], 0.f);
        h1s[mt * 16 + g4 * 4 + r][nbase + nt * 16 + r15] = (f16)v;
      }
  __syncthreads();

  f32x4 acc2[4];
  #pragma unroll
  for (int nt = 0; nt < 4; nt++) {
    float bv = b2[nt * 16 + r15];
    acc2[nt] = (f32x4){bv, bv, bv, bv};
  }
  #pragma unroll
  for (int ks = 0; ks < 8; ks++) {
    int kk = ks * 32 + g4 * 8;
    f16x8 a2 = *(const f16x8*)&h1s[w * 16 + r15][kk];
    #pragma unroll
    for (int nt = 0; nt < 4; nt++) {
      f16x8 bf = *(const f16x8*)&W2t[(size_t)(nt * 16 + r15) * DHID + kk];
      acc2[nt] = __builtin_amdgcn_mfma_f32_16x16x32_f16(a2, bf, acc2[nt], 0, 0, 0);
    }
  }
  float t0 = temp[0];
  #pragma unroll
  for (int nt = 0; nt < 4; nt++)
    #pragma unroll
    for (int r = 0; r < 4; r++) {
      int node = n0 + w * 16 + g4 * 4 + r;
      if (node < NN) {
        int colv = nt * 16 + r15;
        float v = acc2[nt][r];
        h[(size_t)node * DOUT + colv] = (f16)v;
        out[(size_t)node * DOUT + colv] = t0 * v;
      }
    }
}

// ---------------- propagation: hk_next = A_hat hk; out += temp[k]*hk_next --
// One wave per node, lane = feature. Streams (col, out) are nontemporal so
// they don't evict the hk gather working set from L2.
__global__ __launch_bounds__(256) void prop_step(
    const f16* __restrict__ hk, f16* __restrict__ hkn, float* __restrict__ out,
    const int* __restrict__ rs, const int* __restrict__ cnt,
    const int* __restrict__ col, const float* __restrict__ dis,
    const float* __restrict__ temp, int kidx)
{
  int w = blockIdx.x * 4 + (threadIdx.x >> 6);
  int lane = threadIdx.x & 63;
  if (w >= NN) return;
  float dd = dis[w];
  size_t rowoff = (size_t)w * DOUT + lane;
  float a0 = dd * (float)hk[rowoff];  // self-loop (final scale by dd below)
  float a1 = 0.f;
  int beg = rs[w], n = cnt[w];
  const int* cp = col + beg;
  int e = 0;
  for (; e + 8 <= n; e += 8) {
    int c0 = __builtin_nontemporal_load(cp + e + 0);
    int c1 = __builtin_nontemporal_load(cp + e + 1);
    int c2 = __builtin_nontemporal_load(cp + e + 2);
    int c3 = __builtin_nontemporal_load(cp + e + 3);
    int c4 = __builtin_nontemporal_load(cp + e + 4);
    int c5 = __builtin_nontemporal_load(cp + e + 5);
    int c6 = __builtin_nontemporal_load(cp + e + 6);
    int c7 = __builtin_nontemporal_load(cp + e + 7);
    float d0 = dis[c0], d1 = dis[c1], d2 = dis[c2], d3 = dis[c3];
    float d4 = dis[c4], d5 = dis[c5], d6 = dis[c6], d7 = dis[c7];
    float h0 = (float)hk[(size_t)c0 * DOUT + lane];
    float h1 = (float)hk[(size_t)c1 * DOUT + lane];
    float h2 = (float)hk[(size_t)c2 * DOUT + lane];
    float h3 = (float)hk[(size_t)c3 * DOUT + lane];
    float h4 = (float)hk[(size_t)c4 * DOUT + lane];
    float h5 = (float)hk[(size_t)c5 * DOUT + lane];
    float h6 = (float)hk[(size_t)c6 * DOUT + lane];
    float h7 = (float)hk[(size_t)c7 * DOUT + lane];
    a0 = fmaf(d0, h0, a0); a1 = fmaf(d1, h1, a1);
    a0 = fmaf(d2, h2, a0); a1 = fmaf(d3, h3, a1);
    a0 = fmaf(d4, h4, a0); a1 = fmaf(d5, h5, a1);
    a0 = fmaf(d6, h6, a0); a1 = fmaf(d7, h7, a1);
  }
  for (; e < n; ++e) {
    int c = __builtin_nontemporal_load(cp + e);
    a0 = fmaf(dis[c], (float)hk[(size_t)c * DOUT + lane], a0);
  }
  float a = dd * (a0 + a1);
  hkn[rowoff] = (f16)a;
  float ov = __builtin_nontemporal_load(&out[rowoff]);
  __builtin_nontemporal_store(ov + temp[kidx] * a, &out[rowoff]);
}

// ---------------- launch ----------------
extern "C" void kernel_launch(void* const* d_in, const int* in_sizes, int n_in,
                              void* d_out, int out_size, void* d_ws, size_t ws_size,
                              hipStream_t stream) {
  const float* x    = (const float*)d_in[0];
  const int*   ei   = (const int*)d_in[1];
  const float* W1   = (const float*)d_in[2];
  const float* b1   = (const float*)d_in[3];
  const float* W2   = (const float*)d_in[4];
  const float* b2   = (const float*)d_in[5];
  const float* temp = (const float*)d_in[6];
  float* out = (float*)d_out;

  char* wsb = (char*)d_ws;
  size_t off = 0;
  auto carve = [&](size_t bytes) -> void* {
    void* p = wsb + off;
    off = (off + bytes + 255) & ~(size_t)255;
    return p;
  };
  int*   cnt    = (int*)carve((size_t)NN * 4);
  int*   rs     = (int*)carve((size_t)NN * 4);
  int*   cursor = (int*)carve((size_t)NN * 4);
  int*   bsum   = (int*)carve(128 * 4);
  int*   flag   = (int*)carve(256);
  float* dis    = (float*)carve((size_t)NN * 4);
  int*   col    = (int*)carve((size_t)NE * 4);   // 12.8 MB
  f16*   W1t    = (f16*)carve((size_t)DHID * DIN * 2);
  f16*   W2t    = (f16*)carve((size_t)DOUT * DHID * 2);
  f16*   hk_a   = (f16*)carve((size_t)NN * DOUT * 2);
  f16*   hk_b   = (f16*)carve((size_t)NN * DOUT * 2);
  if (off > ws_size) return; // ~41 MB needed

  detect_i64<<<1, 64, 0, stream>>>(ei, flag);
  zero_cnt<<<(NN + 255) / 256, 256, 0, stream>>>(cnt);
  count_deg<<<(NE + 255) / 256, 256, 0, stream>>>(ei, flag, cnt);
  scan1<<<(NN + 1023) / 1024, 1024, 0, stream>>>(cnt, rs, bsum);
  scan2<<<1, 64, 0, stream>>>(bsum, (NN + 1023) / 1024);
  scan3_and_dis<<<(NN + 255) / 256, 256, 0, stream>>>(rs, bsum, cursor, cnt, dis);
  fill_csr<<<(NE + 255) / 256, 256, 0, stream>>>(ei, flag, cursor, col);

  cvt_weights<<<(DIN * DHID + 255) / 256, 256, 0, stream>>>(W1, W2, W1t, W2t);
  mlp_mfma<<<(NN + 63) / 64, 256, 0, stream>>>(x, W1t, b1, W2t, b2, temp, hk_a, out);

  const f16* cur = hk_a;
  f16* nxt = hk_b;
  for (int k = 1; k <= KPROP; k++) {
    prop_step<<<(NN + 3) / 4, 256, 0, stream>>>(cur, nxt, out, rs, cnt, col,
                                                dis, temp, k);
    const f16* t2 = nxt;
    nxt = (f16*)cur;
    cur = t2;
  }
}

// Round 5
// 1390.396 us; speedup vs baseline: 1.5250x; 1.3158x over previous
//
#include <hip/hip_runtime.h>

#define NN 100000
#define NE 3200000
#define DIN 512
#define DHID 256
#define DOUT 64
#define KPROP 10

typedef _Float16 f16;
typedef _Float16 f16x8 __attribute__((ext_vector_type(8)));
typedef _Float16 f16x4 __attribute__((ext_vector_type(4)));
typedef _Float16 f16x2 __attribute__((ext_vector_type(2)));
typedef float f32x4 __attribute__((ext_vector_type(4)));

// ---------------- edge-index layout probe ----------------
__global__ void detect_i64(const int* __restrict__ ei, int* __restrict__ flag) {
  if (blockIdx.x == 0 && threadIdx.x == 0) {
    int z = 1;
    for (int i = 0; i < 512; i++) if (ei[2*i + 1] != 0) { z = 0; break; }
    *flag = z;
  }
}

__device__ __forceinline__ int edge_at(const int* __restrict__ ei, int row, int e, int is64) {
  size_t base = (size_t)row * NE + (size_t)e;
  return is64 ? ei[base * 2] : ei[base];
}

// ---------------- degree count ----------------
__global__ void zero_cnt(int* __restrict__ cnt) {
  int g = blockIdx.x * blockDim.x + threadIdx.x;
  if (g < NN) cnt[g] = 0;
}

// 3.2M atomics over 100k counters = 32/address: low contention (r3 lesson:
// contention scales with ops/ADDRESS — 782-address variant was 3.5x slower).
__global__ void count_deg(const int* __restrict__ ei, const int* __restrict__ flag,
                          int* __restrict__ cnt) {
  int g = blockIdx.x * blockDim.x + threadIdx.x;
  if (g < NE) {
    int d = edge_at(ei, 1, g, *flag);
    atomicAdd(&cnt[d], 1);
  }
}

// ---------------- exclusive scan over cnt ----------------
__global__ void scan1(const int* __restrict__ cnt, int* __restrict__ rs,
                      int* __restrict__ bsum) {
  __shared__ int tmp[1024];
  int t = threadIdx.x;
  int g = blockIdx.x * 1024 + t;
  int v = (g < NN) ? cnt[g] : 0;
  tmp[t] = v;
  __syncthreads();
  for (int off = 1; off < 1024; off <<= 1) {
    int y = (t >= off) ? tmp[t - off] : 0;
    __syncthreads();
    tmp[t] += y;
    __syncthreads();
  }
  if (g < NN) rs[g] = tmp[t] - v;           // exclusive
  if (t == 1023) bsum[blockIdx.x] = tmp[t]; // block total
}

__global__ void scan2(int* __restrict__ bsum, int nb) {
  if (blockIdx.x == 0 && threadIdx.x == 0) {
    int s = 0;
    for (int i = 0; i < nb; i++) { int v = bsum[i]; bsum[i] = s; s += v; }
  }
}

__global__ void scan3_and_dis(int* __restrict__ rs, const int* __restrict__ bsum,
                              int* __restrict__ cursor, const int* __restrict__ cnt,
                              float* __restrict__ dis) {
  int g = blockIdx.x * blockDim.x + threadIdx.x;
  if (g < NN) {
    int v = rs[g] + bsum[g >> 10];
    rs[g] = v;
    cursor[g] = v;
    dis[g] = rsqrtf((float)(cnt[g] + 1)); // +1 self-loop
  }
}

// ---------------- CSR fill (r2-measured-best variant: col + normv) --------
__global__ void fill_csr(const int* __restrict__ ei, const int* __restrict__ flag,
                         const float* __restrict__ dis, int* __restrict__ cursor,
                         int* __restrict__ col, float* __restrict__ normv) {
  int g = blockIdx.x * blockDim.x + threadIdx.x;
  if (g < NE) {
    int is64 = *flag;
    int s = edge_at(ei, 0, g, is64);
    int d = edge_at(ei, 1, g, is64);
    int p = atomicAdd(&cursor[d], 1);
    col[p] = s;
    normv[p] = dis[s] * dis[d];
  }
}

// ---------------- weight transpose + fp16 convert ----------------
__global__ void cvt_weights(const float* __restrict__ W1, const float* __restrict__ W2,
                            f16* __restrict__ W1t, f16* __restrict__ W2t) {
  int g = blockIdx.x * 256 + threadIdx.x;
  if (g < DIN * DHID) {
    int k = g >> 8, n = g & 255;
    W1t[(size_t)n * DIN + k] = (f16)W1[g];
  }
  if (g < DHID * DOUT) {
    int k = g >> 6, n = g & 63;
    W2t[(size_t)n * DHID + k] = (f16)W2[g];
  }
}

// ---------------- fused MLP via f16 MFMA ----------------
__global__ __launch_bounds__(256) void mlp_mfma(
    const float* __restrict__ x, const f16* __restrict__ W1t,
    const float* __restrict__ b1, const f16* __restrict__ W2t,
    const float* __restrict__ b2, const float* __restrict__ temp,
    f16* __restrict__ h, float* __restrict__ out)
{
  __shared__ f16 xs[64][136];
  __shared__ f16 h1s[64][264];
  int t = threadIdx.x;
  int lane = t & 63;
  int w = t >> 6;
  int n0 = blockIdx.x * 64;
  int r15 = lane & 15;
  int g4 = lane >> 4;
  int nbase = w * 64;

  f32x4 acc[4][4];
  #pragma unroll
  for (int nt = 0; nt < 4; nt++) {
    float bv = b1[nbase + nt * 16 + r15];
    #pragma unroll
    for (int mt = 0; mt < 4; mt++) acc[mt][nt] = (f32x4){bv, bv, bv, bv};
  }

  for (int k0 = 0; k0 < DIN; k0 += 128) {
    if (k0) __syncthreads();
    #pragma unroll
    for (int it = 0; it < 8; it++) {
      int m = t + it * 256;
      int row = m >> 5, c4 = m & 31;
      int gr = n0 + row;
      float4 v = (gr < NN) ? *(const float4*)&x[(size_t)gr * DIN + k0 + c4 * 4]
                           : make_float4(0.f, 0.f, 0.f, 0.f);
      f16x4 hv = { (f16)v.x, (f16)v.y, (f16)v.z, (f16)v.w };
      *(f16x4*)&xs[row][c4 * 4] = hv;
    }
    __syncthreads();
    #pragma unroll
    for (int ks = 0; ks < 4; ks++) {
      int kk = ks * 32 + g4 * 8;
      f16x8 a[4], b[4];
      #pragma unroll
      for (int mt = 0; mt < 4; mt++)
        a[mt] = *(const f16x8*)&xs[mt * 16 + r15][kk];
      #pragma unroll
      for (int nt = 0; nt < 4; nt++)
        b[nt] = *(const f16x8*)&W1t[(size_t)(nbase + nt * 16 + r15) * DIN + k0 + kk];
      #pragma unroll
      for (int mt = 0; mt < 4; mt++)
        #pragma unroll
        for (int nt = 0; nt < 4; nt++)
          acc[mt][nt] = __builtin_amdgcn_mfma_f32_16x16x32_f16(a[mt], b[nt], acc[mt][nt], 0, 0, 0);
    }
  }
  #pragma unroll
  for (int mt = 0; mt < 4; mt++)
    #pragma unroll
    for (int nt = 0; nt < 4; nt++)
      #pragma unroll
      for (int r = 0; r < 4; r++) {
        float v = fmaxf(acc[mt][nt][r], 0.f);
        h1s[mt * 16 + g4 * 4 + r][nbase + nt * 16 + r15] = (f16)v;
      }
  __syncthreads();

  f32x4 acc2[4];
  #pragma unroll
  for (int nt = 0; nt < 4; nt++) {
    float bv = b2[nt * 16 + r15];
    acc2[nt] = (f32x4){bv, bv, bv, bv};
  }
  #pragma unroll
  for (int ks = 0; ks < 8; ks++) {
    int kk = ks * 32 + g4 * 8;
    f16x8 a2 = *(const f16x8*)&h1s[w * 16 + r15][kk];
    #pragma unroll
    for (int nt = 0; nt < 4; nt++) {
      f16x8 bf = *(const f16x8*)&W2t[(size_t)(nt * 16 + r15) * DHID + kk];
      acc2[nt] = __builtin_amdgcn_mfma_f32_16x16x32_f16(a2, bf, acc2[nt], 0, 0, 0);
    }
  }
  float t0 = temp[0];
  #pragma unroll
  for (int nt = 0; nt < 4; nt++)
    #pragma unroll
    for (int r = 0; r < 4; r++) {
      int node = n0 + w * 16 + g4 * 4 + r;
      if (node < NN) {
        int colv = nt * 16 + r15;
        float v = acc2[nt][r];
        h[(size_t)node * DOUT + colv] = (f16)v;
        out[(size_t)node * DOUT + colv] = t0 * v;
      }
    }
}

// ---------------- propagation: 4 edges per wave-load ----------------
// One wave per node. Lane layout: q = lane>>4 picks which of 4 edges, s16 =
// lane&15 picks 4 features (8B of the 128B f16 row). One global_load_dwordx2
// fetches 4 neighbor rows -> 4x fewer memory instructions than row-per-load
// (prop is request/latency-bound: r1->r2 byte-halving barely moved it).
// Butterfly (shfl_xor 16,32) combines the 4 quadrant partials at the end.
__global__ __launch_bounds__(256) void prop_step(
    const f16* __restrict__ hk, f16* __restrict__ hkn, float* __restrict__ out,
    const int* __restrict__ rs, const int* __restrict__ cnt,
    const int* __restrict__ col, const float* __restrict__ normv,
    const float* __restrict__ dis, const float* __restrict__ temp, int kidx)
{
  int w = blockIdx.x * 4 + (threadIdx.x >> 6);
  int lane = threadIdx.x & 63;
  if (w >= NN) return;
  int q = lane >> 4;
  int s16 = lane & 15;
  const uint* hk32 = (const uint*)hk;

  f32x4 acc = {0.f, 0.f, 0.f, 0.f};
  int beg = rs[w], n = cnt[w];
  const int* cp = col + beg;
  const float* vp = normv + beg;

  int e = 0;
  for (; e + 8 <= n; e += 8) {
    int c0 = cp[e+0], c1 = cp[e+1], c2 = cp[e+2], c3 = cp[e+3];
    int c4 = cp[e+4], c5 = cp[e+5], c6 = cp[e+6], c7 = cp[e+7];
    float v0 = vp[e+0], v1 = vp[e+1], v2 = vp[e+2], v3 = vp[e+3];
    float v4 = vp[e+4], v5 = vp[e+5], v6 = vp[e+6], v7 = vp[e+7];
    int   ca = q < 2 ? (q == 0 ? c0 : c1) : (q == 2 ? c2 : c3);
    float na = q < 2 ? (q == 0 ? v0 : v1) : (q == 2 ? v2 : v3);
    int   cb = q < 2 ? (q == 0 ? c4 : c5) : (q == 2 ? c6 : c7);
    float nb = q < 2 ? (q == 0 ? v4 : v5) : (q == 2 ? v6 : v7);
    uint2 ha = *(const uint2*)&hk32[(size_t)ca * 32 + s16 * 2];
    uint2 hb = *(const uint2*)&hk32[(size_t)cb * 32 + s16 * 2];
    f16x2 a0 = __builtin_bit_cast(f16x2, ha.x);
    f16x2 a1 = __builtin_bit_cast(f16x2, ha.y);
    f16x2 b0 = __builtin_bit_cast(f16x2, hb.x);
    f16x2 b1 = __builtin_bit_cast(f16x2, hb.y);
    acc[0] = fmaf(na, (float)a0[0], acc[0]);
    acc[1] = fmaf(na, (float)a0[1], acc[1]);
    acc[2] = fmaf(na, (float)a1[0], acc[2]);
    acc[3] = fmaf(na, (float)a1[1], acc[3]);
    acc[0] = fmaf(nb, (float)b0[0], acc[0]);
    acc[1] = fmaf(nb, (float)b0[1], acc[1]);
    acc[2] = fmaf(nb, (float)b1[0], acc[2]);
    acc[3] = fmaf(nb, (float)b1[1], acc[3]);
  }
  for (; e + 4 <= n; e += 4) {
    int c0 = cp[e+0], c1 = cp[e+1], c2 = cp[e+2], c3 = cp[e+3];
    float v0 = vp[e+0], v1 = vp[e+1], v2 = vp[e+2], v3 = vp[e+3];
    int   ca = q < 2 ? (q == 0 ? c0 : c1) : (q == 2 ? c2 : c3);
    float na = q < 2 ? (q == 0 ? v0 : v1) : (q == 2 ? v2 : v3);
    uint2 ha = *(const uint2*)&hk32[(size_t)ca * 32 + s16 * 2];
    f16x2 a0 = __builtin_bit_cast(f16x2, ha.x);
    f16x2 a1 = __builtin_bit_cast(f16x2, ha.y);
    acc[0] = fmaf(na, (float)a0[0], acc[0]);
    acc[1] = fmaf(na, (float)a0[1], acc[1]);
    acc[2] = fmaf(na, (float)a1[0], acc[2]);
    acc[3] = fmaf(na, (float)a1[1], acc[3]);
  }
  // tail (<4 edges): only quadrant 0 contributes (others get weight 0)
  for (; e < n; ++e) {
    int cl = cp[e];
    float na = (q == 0) ? vp[e] : 0.f;
    uint2 ha = *(const uint2*)&hk32[(size_t)cl * 32 + s16 * 2];
    f16x2 a0 = __builtin_bit_cast(f16x2, ha.x);
    f16x2 a1 = __builtin_bit_cast(f16x2, ha.y);
    acc[0] = fmaf(na, (float)a0[0], acc[0]);
    acc[1] = fmaf(na, (float)a0[1], acc[1]);
    acc[2] = fmaf(na, (float)a1[0], acc[2]);
    acc[3] = fmaf(na, (float)a1[1], acc[3]);
  }

  // combine quadrant partials: after this every lane holds the full edge-sum
  #pragma unroll
  for (int i = 0; i < 4; i++) {
    acc[i] += __shfl_xor(acc[i], 16);
    acc[i] += __shfl_xor(acc[i], 32);
  }

  // self-loop: norm = dis[w]^2 (same address all quadrants -> broadcast)
  float dd = dis[w];
  uint2 hs = *(const uint2*)&hk32[(size_t)w * 32 + s16 * 2];
  f16x2 s0 = __builtin_bit_cast(f16x2, hs.x);
  f16x2 s1 = __builtin_bit_cast(f16x2, hs.y);
  float dd2 = dd * dd;
  acc[0] = fmaf(dd2, (float)s0[0], acc[0]);
  acc[1] = fmaf(dd2, (float)s0[1], acc[1]);
  acc[2] = fmaf(dd2, (float)s1[0], acc[2]);
  acc[3] = fmaf(dd2, (float)s1[1], acc[3]);

  if (lane < 16) {
    f16x2 o0 = { (f16)acc[0], (f16)acc[1] };
    f16x2 o1 = { (f16)acc[2], (f16)acc[3] };
    uint2 ov = { __builtin_bit_cast(uint, o0), __builtin_bit_cast(uint, o1) };
    *(uint2*)&((uint*)hkn)[(size_t)w * 32 + s16 * 2] = ov;
    float tk = temp[kidx];
    float4* op = (float4*)&out[(size_t)w * DOUT + s16 * 4];
    float4 o = *op;
    o.x += tk * acc[0];
    o.y += tk * acc[1];
    o.z += tk * acc[2];
    o.w += tk * acc[3];
    *op = o;
  }
}

// ---------------- launch ----------------
extern "C" void kernel_launch(void* const* d_in, const int* in_sizes, int n_in,
                              void* d_out, int out_size, void* d_ws, size_t ws_size,
                              hipStream_t stream) {
  const float* x    = (const float*)d_in[0];
  const int*   ei   = (const int*)d_in[1];
  const float* W1   = (const float*)d_in[2];
  const float* b1   = (const float*)d_in[3];
  const float* W2   = (const float*)d_in[4];
  const float* b2   = (const float*)d_in[5];
  const float* temp = (const float*)d_in[6];
  float* out = (float*)d_out;

  char* wsb = (char*)d_ws;
  size_t off = 0;
  auto carve = [&](size_t bytes) -> void* {
    void* p = wsb + off;
    off = (off + bytes + 255) & ~(size_t)255;
    return p;
  };
  int*   cnt    = (int*)carve((size_t)NN * 4);
  int*   rs     = (int*)carve((size_t)NN * 4);
  int*   cursor = (int*)carve((size_t)NN * 4);
  int*   bsum   = (int*)carve(128 * 4);
  int*   flag   = (int*)carve(256);
  float* dis    = (float*)carve((size_t)NN * 4);
  int*   col    = (int*)carve((size_t)NE * 4);   // 12.8 MB
  float* nv     = (float*)carve((size_t)NE * 4); // 12.8 MB
  f16*   W1t    = (f16*)carve((size_t)DHID * DIN * 2);
  f16*   W2t    = (f16*)carve((size_t)DOUT * DHID * 2);
  f16*   hk_a   = (f16*)carve((size_t)NN * DOUT * 2);
  f16*   hk_b   = (f16*)carve((size_t)NN * DOUT * 2);
  if (off > ws_size) return; // ~54 MB needed

  detect_i64<<<1, 64, 0, stream>>>(ei, flag);
  zero_cnt<<<(NN + 255) / 256, 256, 0, stream>>>(cnt);
  count_deg<<<(NE + 255) / 256, 256, 0, stream>>>(ei, flag, cnt);
  scan1<<<(NN + 1023) / 1024, 1024, 0, stream>>>(cnt, rs, bsum);
  scan2<<<1, 64, 0, stream>>>(bsum, (NN + 1023) / 1024);
  scan3_and_dis<<<(NN + 255) / 256, 256, 0, stream>>>(rs, bsum, cursor, cnt, dis);
  fill_csr<<<(NE + 255) / 256, 256, 0, stream>>>(ei, flag, dis, cursor, col, nv);

  cvt_weights<<<(DIN * DHID + 255) / 256, 256, 0, stream>>>(W1, W2, W1t, W2t);
  mlp_mfma<<<(NN + 63) / 64, 256, 0, stream>>>(x, W1t, b1, W2t, b2, temp, hk_a, out);

  const f16* cur = hk_a;
  f16* nxt = hk_b;
  for (int k = 1; k <= KPROP; k++) {
    prop_step<<<(NN + 3) / 4, 256, 0, stream>>>(cur, nxt, out, rs, cnt, col, nv,
                                                dis, temp, k);
    const f16* t2 = nxt;
    nxt = (f16*)cur;
    cur = t2;
  }
}

// Round 6
// 1069.508 us; speedup vs baseline: 1.9826x; 1.3000x over previous
//
#include <hip/hip_runtime.h>

#define NN 100000
#define NE 3200000
#define DIN 512
#define DHID 256
#define DOUT 64
#define KPROP 10

typedef _Float16 f16;
typedef _Float16 f16x8 __attribute__((ext_vector_type(8)));
typedef _Float16 f16x4 __attribute__((ext_vector_type(4)));
typedef float f32x4 __attribute__((ext_vector_type(4)));

// ---------------- edge-index layout probe (wave-parallel) ----------------
__global__ void detect_i64(const int* __restrict__ ei, int* __restrict__ flag) {
  int lane = threadIdx.x;
  int ok = 1;
  for (int i = lane; i < 512; i += 64)
    if (ei[2 * i + 1] != 0) ok = 0;
  ok = __all(ok);
  if (lane == 0) *flag = ok;
}

// ---------------- degree count: 4 edges/thread, vectorized ----------------
__global__ void zero_cnt(int* __restrict__ cnt) {
  int g = blockIdx.x * blockDim.x + threadIdx.x;
  if (g < NN) cnt[g] = 0;
}

// 3.2M atomics over 100k counters = 32/address: low contention (r3 lesson:
// contention scales with ops/ADDRESS — 782-address variant was 3.5x slower).
__global__ void count_deg(const int* __restrict__ ei, const int* __restrict__ flag,
                          int* __restrict__ cnt) {
  int g = blockIdx.x * blockDim.x + threadIdx.x;
  int e0 = g * 4;
  if (e0 >= NE) return;
  int is64 = *flag;
  int d0, d1, d2, d3;
  if (is64) {
    int4 a = *(const int4*)&ei[2 * (size_t)NE + 2 * (size_t)e0];
    int4 b = *(const int4*)&ei[2 * (size_t)NE + 2 * (size_t)e0 + 4];
    d0 = a.x; d1 = a.z; d2 = b.x; d3 = b.z;
  } else {
    int4 a = *(const int4*)&ei[(size_t)NE + e0];
    d0 = a.x; d1 = a.y; d2 = a.z; d3 = a.w;
  }
  atomicAdd(&cnt[d0], 1);
  atomicAdd(&cnt[d1], 1);
  atomicAdd(&cnt[d2], 1);
  atomicAdd(&cnt[d3], 1);
}

// ---------------- exclusive scan over cnt ----------------
__global__ void scan1(const int* __restrict__ cnt, int* __restrict__ rs,
                      int* __restrict__ bsum) {
  __shared__ int tmp[1024];
  int t = threadIdx.x;
  int g = blockIdx.x * 1024 + t;
  int v = (g < NN) ? cnt[g] : 0;
  tmp[t] = v;
  __syncthreads();
  for (int off = 1; off < 1024; off <<= 1) {
    int y = (t >= off) ? tmp[t - off] : 0;
    __syncthreads();
    tmp[t] += y;
    __syncthreads();
  }
  if (g < NN) rs[g] = tmp[t] - v;           // exclusive
  if (t == 1023) bsum[blockIdx.x] = tmp[t]; // block total
}

__global__ void scan2(int* __restrict__ bsum, int nb) {
  if (blockIdx.x == 0 && threadIdx.x == 0) {
    int s = 0;
    for (int i = 0; i < nb; i++) { int v = bsum[i]; bsum[i] = s; s += v; }
  }
}

__global__ void scan3_and_dis(int* __restrict__ rs, const int* __restrict__ bsum,
                              int* __restrict__ cursor, const int* __restrict__ cnt,
                              float* __restrict__ dis) {
  int g = blockIdx.x * blockDim.x + threadIdx.x;
  if (g < NN) {
    int v = rs[g] + bsum[g >> 10];
    rs[g] = v;
    cursor[g] = v;
    dis[g] = rsqrtf((float)(cnt[g] + 1)); // +1 self-loop
  }
}

// ---------------- CSR fill: combined {col, norm} 8B record ----------------
// One 8B store per edge (vs 2x4B to two arrays): half the dirty lines,
// double the bytes per line -> less partial-line writeback amplification.
__global__ void fill_csr(const int* __restrict__ ei, const int* __restrict__ flag,
                         const float* __restrict__ dis, int* __restrict__ cursor,
                         int2* __restrict__ recs) {
  int g = blockIdx.x * blockDim.x + threadIdx.x;
  int e0 = g * 2;
  if (e0 >= NE) return;
  int is64 = *flag;
  int s0, s1, d0, d1;
  if (is64) {
    int4 sv = *(const int4*)&ei[2 * (size_t)e0];
    int4 dv = *(const int4*)&ei[2 * (size_t)NE + 2 * (size_t)e0];
    s0 = sv.x; s1 = sv.z; d0 = dv.x; d1 = dv.z;
  } else {
    int2 sv = *(const int2*)&ei[e0];
    int2 dv = *(const int2*)&ei[(size_t)NE + e0];
    s0 = sv.x; s1 = sv.y; d0 = dv.x; d1 = dv.y;
  }
  int p0 = atomicAdd(&cursor[d0], 1);
  recs[p0] = make_int2(s0, __float_as_int(dis[s0] * dis[d0]));
  int p1 = atomicAdd(&cursor[d1], 1);
  recs[p1] = make_int2(s1, __float_as_int(dis[s1] * dis[d1]));
}

// ---------------- weight transpose + fp16 convert ----------------
__global__ void cvt_weights(const float* __restrict__ W1, const float* __restrict__ W2,
                            f16* __restrict__ W1t, f16* __restrict__ W2t) {
  int g = blockIdx.x * 256 + threadIdx.x;
  if (g < DIN * DHID) {
    int k = g >> 8, n = g & 255;
    W1t[(size_t)n * DIN + k] = (f16)W1[g];
  }
  if (g < DHID * DOUT) {
    int k = g >> 6, n = g & 63;
    W2t[(size_t)n * DHID + k] = (f16)W2[g];
  }
}

// ---------------- fused MLP via f16 MFMA ----------------
// Writes h (f16) and the Horner seed z = temp[K]*h (f16).
__global__ __launch_bounds__(256) void mlp_mfma(
    const float* __restrict__ x, const f16* __restrict__ W1t,
    const float* __restrict__ b1, const f16* __restrict__ W2t,
    const float* __restrict__ b2, const float* __restrict__ temp,
    f16* __restrict__ h, f16* __restrict__ z)
{
  __shared__ f16 xs[64][136];
  __shared__ f16 h1s[64][264];
  int t = threadIdx.x;
  int lane = t & 63;
  int w = t >> 6;
  int n0 = blockIdx.x * 64;
  int r15 = lane & 15;
  int g4 = lane >> 4;
  int nbase = w * 64;

  f32x4 acc[4][4];
  #pragma unroll
  for (int nt = 0; nt < 4; nt++) {
    float bv = b1[nbase + nt * 16 + r15];
    #pragma unroll
    for (int mt = 0; mt < 4; mt++) acc[mt][nt] = (f32x4){bv, bv, bv, bv};
  }

  for (int k0 = 0; k0 < DIN; k0 += 128) {
    if (k0) __syncthreads();
    #pragma unroll
    for (int it = 0; it < 8; it++) {
      int m = t + it * 256;
      int row = m >> 5, c4 = m & 31;
      int gr = n0 + row;
      float4 v = (gr < NN) ? *(const float4*)&x[(size_t)gr * DIN + k0 + c4 * 4]
                           : make_float4(0.f, 0.f, 0.f, 0.f);
      f16x4 hv = { (f16)v.x, (f16)v.y, (f16)v.z, (f16)v.w };
      *(f16x4*)&xs[row][c4 * 4] = hv;
    }
    __syncthreads();
    #pragma unroll
    for (int ks = 0; ks < 4; ks++) {
      int kk = ks * 32 + g4 * 8;
      f16x8 a[4], b[4];
      #pragma unroll
      for (int mt = 0; mt < 4; mt++)
        a[mt] = *(const f16x8*)&xs[mt * 16 + r15][kk];
      #pragma unroll
      for (int nt = 0; nt < 4; nt++)
        b[nt] = *(const f16x8*)&W1t[(size_t)(nbase + nt * 16 + r15) * DIN + k0 + kk];
      #pragma unroll
      for (int mt = 0; mt < 4; mt++)
        #pragma unroll
        for (int nt = 0; nt < 4; nt++)
          acc[mt][nt] = __builtin_amdgcn_mfma_f32_16x16x32_f16(a[mt], b[nt], acc[mt][nt], 0, 0, 0);
    }
  }
  #pragma unroll
  for (int mt = 0; mt < 4; mt++)
    #pragma unroll
    for (int nt = 0; nt < 4; nt++)
      #pragma unroll
      for (int r = 0; r < 4; r++) {
        float v = fmaxf(acc[mt][nt][r], 0.f);
        h1s[mt * 16 + g4 * 4 + r][nbase + nt * 16 + r15] = (f16)v;
      }
  __syncthreads();

  f32x4 acc2[4];
  #pragma unroll
  for (int nt = 0; nt < 4; nt++) {
    float bv = b2[nt * 16 + r15];
    acc2[nt] = (f32x4){bv, bv, bv, bv};
  }
  #pragma unroll
  for (int ks = 0; ks < 8; ks++) {
    int kk = ks * 32 + g4 * 8;
    f16x8 a2 = *(const f16x8*)&h1s[w * 16 + r15][kk];
    #pragma unroll
    for (int nt = 0; nt < 4; nt++) {
      f16x8 bf = *(const f16x8*)&W2t[(size_t)(nt * 16 + r15) * DHID + kk];
      acc2[nt] = __builtin_amdgcn_mfma_f32_16x16x32_f16(a2, bf, acc2[nt], 0, 0, 0);
    }
  }
  float tK = temp[KPROP];
  #pragma unroll
  for (int nt = 0; nt < 4; nt++)
    #pragma unroll
    for (int r = 0; r < 4; r++) {
      int node = n0 + w * 16 + g4 * 4 + r;
      if (node < NN) {
        int colv = nt * 16 + r15;
        float v = acc2[nt][r];
        h[(size_t)node * DOUT + colv] = (f16)v;
        z[(size_t)node * DOUT + colv] = (f16)(tK * v);
      }
    }
}

// ---------------- Horner propagation: z_new = temp[k]*h + A_hat z ----------
// One wave per node. q = lane>>3 picks one of 8 edges, s8 = lane&7 picks a
// 16B feature octet: one global_load_dwordx4 fetches 8 neighbor rows (prop is
// request-bound, r5-confirmed). Edge records {col,norm} are a single 8B
// stream. Butterfly xor(8,16,32) combines; final step writes f32 out.
__global__ __launch_bounds__(256) void prop_horner(
    const f16* __restrict__ z, f16* __restrict__ zn, const f16* __restrict__ h,
    float* __restrict__ out, const int* __restrict__ rs, const int* __restrict__ cnt,
    const int2* __restrict__ recs, const float* __restrict__ dis,
    const float* __restrict__ temp, int kidx, int final_step)
{
  int w = blockIdx.x * 4 + (threadIdx.x >> 6);
  int lane = threadIdx.x & 63;
  if (w >= NN) return;
  int q = lane >> 3;
  int s8 = lane & 7;

  float acc[8];
  #pragma unroll
  for (int f = 0; f < 8; f++) acc[f] = 0.f;

  int beg = rs[w], n = cnt[w];
  const int2* rp = recs + beg;

  int e = 0;
  for (; e + 16 <= n; e += 16) {
    int2 r0 = rp[e + q];
    int2 r1 = rp[e + 8 + q];
    f16x8 g0 = *(const f16x8*)&z[(size_t)r0.x * DOUT + s8 * 8];
    f16x8 g1 = *(const f16x8*)&z[(size_t)r1.x * DOUT + s8 * 8];
    float w0 = __int_as_float(r0.y);
    float w1 = __int_as_float(r1.y);
    #pragma unroll
    for (int f = 0; f < 8; f++) acc[f] = fmaf(w0, (float)g0[f], acc[f]);
    #pragma unroll
    for (int f = 0; f < 8; f++) acc[f] = fmaf(w1, (float)g1[f], acc[f]);
  }
  for (; e + 8 <= n; e += 8) {
    int2 r0 = rp[e + q];
    f16x8 g0 = *(const f16x8*)&z[(size_t)r0.x * DOUT + s8 * 8];
    float w0 = __int_as_float(r0.y);
    #pragma unroll
    for (int f = 0; f < 8; f++) acc[f] = fmaf(w0, (float)g0[f], acc[f]);
  }
  if (e < n) {
    int rem = n - e;
    int qq = q < rem ? q : rem - 1;   // clamp; invalid slots get weight 0
    int2 r0 = rp[e + qq];
    f16x8 g0 = *(const f16x8*)&z[(size_t)r0.x * DOUT + s8 * 8];
    float w0 = (q < rem) ? __int_as_float(r0.y) : 0.f;
    #pragma unroll
    for (int f = 0; f < 8; f++) acc[f] = fmaf(w0, (float)g0[f], acc[f]);
  }

  // combine 8 edge-slot partials -> every lane holds full edge sums
  #pragma unroll
  for (int f = 0; f < 8; f++) {
    acc[f] += __shfl_xor(acc[f], 8);
    acc[f] += __shfl_xor(acc[f], 16);
    acc[f] += __shfl_xor(acc[f], 32);
  }

  if (q == 0) {
    float dd = dis[w];
    float dd2 = dd * dd;              // self-loop norm
    float gk = temp[kidx];
    f16x8 zs = *(const f16x8*)&z[(size_t)w * DOUT + s8 * 8];
    f16x8 hs = *(const f16x8*)&h[(size_t)w * DOUT + s8 * 8];
    #pragma unroll
    for (int f = 0; f < 8; f++)
      acc[f] += dd2 * (float)zs[f] + gk * (float)hs[f];
    if (final_step) {
      float4 o0 = { acc[0], acc[1], acc[2], acc[3] };
      float4 o1 = { acc[4], acc[5], acc[6], acc[7] };
      *(float4*)&out[(size_t)w * DOUT + s8 * 8] = o0;
      *(float4*)&out[(size_t)w * DOUT + s8 * 8 + 4] = o1;
    } else {
      f16x8 o;
      #pragma unroll
      for (int f = 0; f < 8; f++) o[f] = (f16)acc[f];
      *(f16x8*)&zn[(size_t)w * DOUT + s8 * 8] = o;
    }
  }
}

// ---------------- launch ----------------
extern "C" void kernel_launch(void* const* d_in, const int* in_sizes, int n_in,
                              void* d_out, int out_size, void* d_ws, size_t ws_size,
                              hipStream_t stream) {
  const float* x    = (const float*)d_in[0];
  const int*   ei   = (const int*)d_in[1];
  const float* W1   = (const float*)d_in[2];
  const float* b1   = (const float*)d_in[3];
  const float* W2   = (const float*)d_in[4];
  const float* b2   = (const float*)d_in[5];
  const float* temp = (const float*)d_in[6];
  float* out = (float*)d_out;

  char* wsb = (char*)d_ws;
  size_t off = 0;
  auto carve = [&](size_t bytes) -> void* {
    void* p = wsb + off;
    off = (off + bytes + 255) & ~(size_t)255;
    return p;
  };
  int*   cnt    = (int*)carve((size_t)NN * 4);
  int*   rs     = (int*)carve((size_t)NN * 4);
  int*   cursor = (int*)carve((size_t)NN * 4);
  int*   bsum   = (int*)carve(128 * 4);
  int*   flag   = (int*)carve(256);
  float* dis    = (float*)carve((size_t)NN * 4);
  int2*  recs   = (int2*)carve((size_t)NE * 8);  // 25.6 MB
  f16*   W1t    = (f16*)carve((size_t)DHID * DIN * 2);
  f16*   W2t    = (f16*)carve((size_t)DOUT * DHID * 2);
  f16*   h_buf  = (f16*)carve((size_t)NN * DOUT * 2);
  f16*   z_a    = (f16*)carve((size_t)NN * DOUT * 2);
  f16*   z_b    = (f16*)carve((size_t)NN * DOUT * 2);
  if (off > ws_size) return; // ~67 MB needed

  detect_i64<<<1, 64, 0, stream>>>(ei, flag);
  zero_cnt<<<(NN + 255) / 256, 256, 0, stream>>>(cnt);
  count_deg<<<(NE / 4 + 255) / 256, 256, 0, stream>>>(ei, flag, cnt);
  scan1<<<(NN + 1023) / 1024, 1024, 0, stream>>>(cnt, rs, bsum);
  scan2<<<1, 64, 0, stream>>>(bsum, (NN + 1023) / 1024);
  scan3_and_dis<<<(NN + 255) / 256, 256, 0, stream>>>(rs, bsum, cursor, cnt, dis);
  fill_csr<<<(NE / 2 + 255) / 256, 256, 0, stream>>>(ei, flag, dis, cursor, recs);

  cvt_weights<<<(DIN * DHID + 255) / 256, 256, 0, stream>>>(W1, W2, W1t, W2t);
  mlp_mfma<<<(NN + 63) / 64, 256, 0, stream>>>(x, W1t, b1, W2t, b2, temp, h_buf, z_a);

  const f16* zc = z_a;
  f16* zn = z_b;
  for (int k = KPROP - 1; k >= 0; k--) {
    prop_horner<<<(NN + 3) / 4, 256, 0, stream>>>(zc, zn, h_buf, out, rs, cnt,
                                                  recs, dis, temp, k, k == 0);
    const f16* t2 = zn;
    zn = (f16*)zc;
    zc = t2;
  }
}

// Round 7
// 1030.562 us; speedup vs baseline: 2.0575x; 1.0378x over previous
//
#include <hip/hip_runtime.h>

#define NN 100000
#define NE 3200000
#define DIN 512
#define DHID 256
#define DOUT 64
#define KPROP 10

typedef _Float16 f16;
typedef _Float16 f16x8 __attribute__((ext_vector_type(8)));
typedef _Float16 f16x4 __attribute__((ext_vector_type(4)));
typedef float f32x4 __attribute__((ext_vector_type(4)));

// ---------------- edge-index layout probe (wave-parallel) ----------------
__global__ void detect_i64(const int* __restrict__ ei, int* __restrict__ flag) {
  int lane = threadIdx.x;
  int ok = 1;
  for (int i = lane; i < 512; i += 64)
    if (ei[2 * i + 1] != 0) ok = 0;
  ok = __all(ok);
  if (lane == 0) *flag = ok;
}

// ---------------- degree count: 4 edges/thread, vectorized ----------------
__global__ void zero_cnt(int* __restrict__ cnt) {
  int g = blockIdx.x * blockDim.x + threadIdx.x;
  if (g < NN) cnt[g] = 0;
}

// 3.2M atomics over 100k counters = 32/address: low contention (r3 lesson:
// contention scales with ops/ADDRESS — 782-address variant was 3.5x slower).
__global__ void count_deg(const int* __restrict__ ei, const int* __restrict__ flag,
                          int* __restrict__ cnt) {
  int g = blockIdx.x * blockDim.x + threadIdx.x;
  int e0 = g * 4;
  if (e0 >= NE) return;
  int is64 = *flag;
  int d0, d1, d2, d3;
  if (is64) {
    int4 a = *(const int4*)&ei[2 * (size_t)NE + 2 * (size_t)e0];
    int4 b = *(const int4*)&ei[2 * (size_t)NE + 2 * (size_t)e0 + 4];
    d0 = a.x; d1 = a.z; d2 = b.x; d3 = b.z;
  } else {
    int4 a = *(const int4*)&ei[(size_t)NE + e0];
    d0 = a.x; d1 = a.y; d2 = a.z; d3 = a.w;
  }
  atomicAdd(&cnt[d0], 1);
  atomicAdd(&cnt[d1], 1);
  atomicAdd(&cnt[d2], 1);
  atomicAdd(&cnt[d3], 1);
}

// ---------------- exclusive scan over cnt ----------------
__global__ void scan1(const int* __restrict__ cnt, int* __restrict__ rs,
                      int* __restrict__ bsum) {
  __shared__ int tmp[1024];
  int t = threadIdx.x;
  int g = blockIdx.x * 1024 + t;
  int v = (g < NN) ? cnt[g] : 0;
  tmp[t] = v;
  __syncthreads();
  for (int off = 1; off < 1024; off <<= 1) {
    int y = (t >= off) ? tmp[t - off] : 0;
    __syncthreads();
    tmp[t] += y;
    __syncthreads();
  }
  if (g < NN) rs[g] = tmp[t] - v;           // exclusive
  if (t == 1023) bsum[blockIdx.x] = tmp[t]; // block total
}

__global__ void scan2(int* __restrict__ bsum, int nb) {
  if (blockIdx.x == 0 && threadIdx.x == 0) {
    int s = 0;
    for (int i = 0; i < nb; i++) { int v = bsum[i]; bsum[i] = s; s += v; }
  }
}

__global__ void scan3_and_dis(int* __restrict__ rs, const int* __restrict__ bsum,
                              int* __restrict__ cursor, const int* __restrict__ cnt,
                              float* __restrict__ dis) {
  int g = blockIdx.x * blockDim.x + threadIdx.x;
  if (g < NN) {
    int v = rs[g] + bsum[g >> 10];
    rs[g] = v;
    cursor[g] = v;
    dis[g] = rsqrtf((float)(cnt[g] + 1)); // +1 self-loop
  }
}

// ---------------- CSR fill: combined {col, norm} 8B record ----------------
// One 8B store per edge (vs 2x4B to two arrays): half the dirty lines,
// double the bytes per line -> less partial-line writeback amplification.
__global__ void fill_csr(const int* __restrict__ ei, const int* __restrict__ flag,
                         const float* __restrict__ dis, int* __restrict__ cursor,
                         int2* __restrict__ recs) {
  int g = blockIdx.x * blockDim.x + threadIdx.x;
  int e0 = g * 2;
  if (e0 >= NE) return;
  int is64 = *flag;
  int s0, s1, d0, d1;
  if (is64) {
    int4 sv = *(const int4*)&ei[2 * (size_t)e0];
    int4 dv = *(const int4*)&ei[2 * (size_t)NE + 2 * (size_t)e0];
    s0 = sv.x; s1 = sv.z; d0 = dv.x; d1 = dv.z;
  } else {
    int2 sv = *(const int2*)&ei[e0];
    int2 dv = *(const int2*)&ei[(size_t)NE + e0];
    s0 = sv.x; s1 = sv.y; d0 = dv.x; d1 = dv.y;
  }
  int p0 = atomicAdd(&cursor[d0], 1);
  recs[p0] = make_int2(s0, __float_as_int(dis[s0] * dis[d0]));
  int p1 = atomicAdd(&cursor[d1], 1);
  recs[p1] = make_int2(s1, __float_as_int(dis[s1] * dis[d1]));
}

// ---------------- weight transpose + fp16 convert ----------------
__global__ void cvt_weights(const float* __restrict__ W1, const float* __restrict__ W2,
                            f16* __restrict__ W1t, f16* __restrict__ W2t) {
  int g = blockIdx.x * 256 + threadIdx.x;
  if (g < DIN * DHID) {
    int k = g >> 8, n = g & 255;
    W1t[(size_t)n * DIN + k] = (f16)W1[g];
  }
  if (g < DHID * DOUT) {
    int k = g >> 6, n = g & 63;
    W2t[(size_t)n * DHID + k] = (f16)W2[g];
  }
}

// ---------------- fused MLP via f16 MFMA (pipelined, union LDS) ----------
// LDS union: xs double-buffer [2][64][136] f16 (34816B) aliases h1s[64][264]
// (33792B) — h1s only live after all xs reads. 4 blocks/CU (was 3).
// Staging pipelined: issue chunk c+1 global loads -> regs, compute chunk c,
// ds_write c+1, ONE barrier per chunk (was 2) — HBM latency hides under MFMA.
__global__ __launch_bounds__(256) void mlp_mfma(
    const float* __restrict__ x, const f16* __restrict__ W1t,
    const float* __restrict__ b1, const f16* __restrict__ W2t,
    const float* __restrict__ b2, const float* __restrict__ temp,
    f16* __restrict__ h, f16* __restrict__ z)
{
  __shared__ __align__(16) char smraw[2 * 64 * 136 * 2]; // 34816 B
  f16* xsb = (f16*)smraw;          // xs[buf][row][136]: buf*8704 + row*136 + col
  f16* h1s = (f16*)smraw;          // h1s[row][264]: row*264 + col
  int t = threadIdx.x;
  int lane = t & 63;
  int w = t >> 6;
  int n0 = blockIdx.x * 64;
  int r15 = lane & 15;
  int g4 = lane >> 4;
  int nbase = w * 64;
  int srow = t >> 5, sc4 = t & 31;  // staging: thread -> (row base, float4 col)

  f32x4 acc[4][4];
  #pragma unroll
  for (int nt = 0; nt < 4; nt++) {
    float bv = b1[nbase + nt * 16 + r15];
    #pragma unroll
    for (int mt = 0; mt < 4; mt++) acc[mt][nt] = (f32x4){bv, bv, bv, bv};
  }

  float4 ld[8];
  // stage chunk 0
  #pragma unroll
  for (int it = 0; it < 8; it++) {
    int row = srow + it * 8;
    int gr = n0 + row;
    ld[it] = (gr < NN) ? *(const float4*)&x[(size_t)gr * DIN + sc4 * 4]
                       : make_float4(0.f, 0.f, 0.f, 0.f);
  }
  #pragma unroll
  for (int it = 0; it < 8; it++) {
    int row = srow + it * 8;
    f16x4 hv = { (f16)ld[it].x, (f16)ld[it].y, (f16)ld[it].z, (f16)ld[it].w };
    *(f16x4*)&xsb[row * 136 + sc4 * 4] = hv;
  }
  __syncthreads();

  for (int c = 0; c < 4; c++) {
    int cur = c & 1;
    if (c < 3) {  // issue next chunk's loads (latency hides under compute)
      #pragma unroll
      for (int it = 0; it < 8; it++) {
        int row = srow + it * 8;
        int gr = n0 + row;
        ld[it] = (gr < NN)
            ? *(const float4*)&x[(size_t)gr * DIN + (c + 1) * 128 + sc4 * 4]
            : make_float4(0.f, 0.f, 0.f, 0.f);
      }
    }
    int k0 = c * 128;
    const f16* xs = xsb + cur * 8704;
    #pragma unroll
    for (int ks = 0; ks < 4; ks++) {
      int kk = ks * 32 + g4 * 8;
      f16x8 a[4], b[4];
      #pragma unroll
      for (int mt = 0; mt < 4; mt++)
        a[mt] = *(const f16x8*)&xs[(mt * 16 + r15) * 136 + kk];
      #pragma unroll
      for (int nt = 0; nt < 4; nt++)
        b[nt] = *(const f16x8*)&W1t[(size_t)(nbase + nt * 16 + r15) * DIN + k0 + kk];
      #pragma unroll
      for (int mt = 0; mt < 4; mt++)
        #pragma unroll
        for (int nt = 0; nt < 4; nt++)
          acc[mt][nt] = __builtin_amdgcn_mfma_f32_16x16x32_f16(a[mt], b[nt], acc[mt][nt], 0, 0, 0);
    }
    if (c < 3) {
      #pragma unroll
      for (int it = 0; it < 8; it++) {
        int row = srow + it * 8;
        f16x4 hv = { (f16)ld[it].x, (f16)ld[it].y, (f16)ld[it].z, (f16)ld[it].w };
        *(f16x4*)&xsb[(cur ^ 1) * 8704 + row * 136 + sc4 * 4] = hv;
      }
    }
    __syncthreads();  // also separates last xs read from h1s writes below
  }

  // relu -> h1s f16 (D layout: col = lane&15, row = g4*4+reg [m89-verified])
  #pragma unroll
  for (int mt = 0; mt < 4; mt++)
    #pragma unroll
    for (int nt = 0; nt < 4; nt++)
      #pragma unroll
      for (int r = 0; r < 4; r++) {
        float v = fmaxf(acc[mt][nt][r], 0.f);
        h1s[(mt * 16 + g4 * 4 + r) * 264 + nbase + nt * 16 + r15] = (f16)v;
      }
  __syncthreads();

  f32x4 acc2[4];
  #pragma unroll
  for (int nt = 0; nt < 4; nt++) {
    float bv = b2[nt * 16 + r15];
    acc2[nt] = (f32x4){bv, bv, bv, bv};
  }
  #pragma unroll
  for (int ks = 0; ks < 8; ks++) {
    int kk = ks * 32 + g4 * 8;
    f16x8 a2 = *(const f16x8*)&h1s[(w * 16 + r15) * 264 + kk];
    #pragma unroll
    for (int nt = 0; nt < 4; nt++) {
      f16x8 bf = *(const f16x8*)&W2t[(size_t)(nt * 16 + r15) * DHID + kk];
      acc2[nt] = __builtin_amdgcn_mfma_f32_16x16x32_f16(a2, bf, acc2[nt], 0, 0, 0);
    }
  }
  float tK = temp[KPROP];
  #pragma unroll
  for (int nt = 0; nt < 4; nt++)
    #pragma unroll
    for (int r = 0; r < 4; r++) {
      int node = n0 + w * 16 + g4 * 4 + r;
      if (node < NN) {
        int colv = nt * 16 + r15;
        float v = acc2[nt][r];
        h[(size_t)node * DOUT + colv] = (f16)v;
        z[(size_t)node * DOUT + colv] = (f16)(tK * v);
      }
    }
}

// ---------------- Horner propagation: z_new = temp[k]*h + A_hat z ----------
// One wave per node. q = lane>>3 picks one of 8 edges, s8 = lane&7 picks a
// 16B feature octet: one global_load_dwordx4 fetches 8 neighbor rows. Main
// loop covers 32 edges (4 gathers in flight/lane — prop is request/latency
// bound, r5/r6-confirmed; avg degree 32 -> 1 main iter/node). Butterfly
// xor(8,16,32) combines; final step writes f32 out.
__global__ __launch_bounds__(256) void prop_horner(
    const f16* __restrict__ z, f16* __restrict__ zn, const f16* __restrict__ h,
    float* __restrict__ out, const int* __restrict__ rs, const int* __restrict__ cnt,
    const int2* __restrict__ recs, const float* __restrict__ dis,
    const float* __restrict__ temp, int kidx, int final_step)
{
  int w = blockIdx.x * 4 + (threadIdx.x >> 6);
  int lane = threadIdx.x & 63;
  if (w >= NN) return;
  int q = lane >> 3;
  int s8 = lane & 7;

  float acc[8];
  #pragma unroll
  for (int f = 0; f < 8; f++) acc[f] = 0.f;

  int beg = rs[w], n = cnt[w];
  const int2* rp = recs + beg;

  int e = 0;
  for (; e + 32 <= n; e += 32) {
    int2 r0 = rp[e + q];
    int2 r1 = rp[e + 8 + q];
    int2 r2 = rp[e + 16 + q];
    int2 r3 = rp[e + 24 + q];
    f16x8 g0 = *(const f16x8*)&z[(size_t)r0.x * DOUT + s8 * 8];
    f16x8 g1 = *(const f16x8*)&z[(size_t)r1.x * DOUT + s8 * 8];
    f16x8 g2 = *(const f16x8*)&z[(size_t)r2.x * DOUT + s8 * 8];
    f16x8 g3 = *(const f16x8*)&z[(size_t)r3.x * DOUT + s8 * 8];
    float w0 = __int_as_float(r0.y);
    float w1 = __int_as_float(r1.y);
    float w2 = __int_as_float(r2.y);
    float w3 = __int_as_float(r3.y);
    #pragma unroll
    for (int f = 0; f < 8; f++) acc[f] = fmaf(w0, (float)g0[f], acc[f]);
    #pragma unroll
    for (int f = 0; f < 8; f++) acc[f] = fmaf(w1, (float)g1[f], acc[f]);
    #pragma unroll
    for (int f = 0; f < 8; f++) acc[f] = fmaf(w2, (float)g2[f], acc[f]);
    #pragma unroll
    for (int f = 0; f < 8; f++) acc[f] = fmaf(w3, (float)g3[f], acc[f]);
  }
  for (; e + 8 <= n; e += 8) {
    int2 r0 = rp[e + q];
    f16x8 g0 = *(const f16x8*)&z[(size_t)r0.x * DOUT + s8 * 8];
    float w0 = __int_as_float(r0.y);
    #pragma unroll
    for (int f = 0; f < 8; f++) acc[f] = fmaf(w0, (float)g0[f], acc[f]);
  }
  if (e < n) {
    int rem = n - e;
    int qq = q < rem ? q : rem - 1;   // clamp; invalid slots get weight 0
    int2 r0 = rp[e + qq];
    f16x8 g0 = *(const f16x8*)&z[(size_t)r0.x * DOUT + s8 * 8];
    float w0 = (q < rem) ? __int_as_float(r0.y) : 0.f;
    #pragma unroll
    for (int f = 0; f < 8; f++) acc[f] = fmaf(w0, (float)g0[f], acc[f]);
  }

  // combine 8 edge-slot partials -> every lane holds full edge sums
  #pragma unroll
  for (int f = 0; f < 8; f++) {
    acc[f] += __shfl_xor(acc[f], 8);
    acc[f] += __shfl_xor(acc[f], 16);
    acc[f] += __shfl_xor(acc[f], 32);
  }

  if (q == 0) {
    float dd = dis[w];
    float dd2 = dd * dd;              // self-loop norm
    float gk = temp[kidx];
    f16x8 zs = *(const f16x8*)&z[(size_t)w * DOUT + s8 * 8];
    f16x8 hs = *(const f16x8*)&h[(size_t)w * DOUT + s8 * 8];
    #pragma unroll
    for (int f = 0; f < 8; f++)
      acc[f] += dd2 * (float)zs[f] + gk * (float)hs[f];
    if (final_step) {
      float4 o0 = { acc[0], acc[1], acc[2], acc[3] };
      float4 o1 = { acc[4], acc[5], acc[6], acc[7] };
      *(float4*)&out[(size_t)w * DOUT + s8 * 8] = o0;
      *(float4*)&out[(size_t)w * DOUT + s8 * 8 + 4] = o1;
    } else {
      f16x8 o;
      #pragma unroll
      for (int f = 0; f < 8; f++) o[f] = (f16)acc[f];
      *(f16x8*)&zn[(size_t)w * DOUT + s8 * 8] = o;
    }
  }
}

// ---------------- launch ----------------
extern "C" void kernel_launch(void* const* d_in, const int* in_sizes, int n_in,
                              void* d_out, int out_size, void* d_ws, size_t ws_size,
                              hipStream_t stream) {
  const float* x    = (const float*)d_in[0];
  const int*   ei   = (const int*)d_in[1];
  const float* W1   = (const float*)d_in[2];
  const float* b1   = (const float*)d_in[3];
  const float* W2   = (const float*)d_in[4];
  const float* b2   = (const float*)d_in[5];
  const float* temp = (const float*)d_in[6];
  float* out = (float*)d_out;

  char* wsb = (char*)d_ws;
  size_t off = 0;
  auto carve = [&](size_t bytes) -> void* {
    void* p = wsb + off;
    off = (off + bytes + 255) & ~(size_t)255;
    return p;
  };
  int*   cnt    = (int*)carve((size_t)NN * 4);
  int*   rs     = (int*)carve((size_t)NN * 4);
  int*   cursor = (int*)carve((size_t)NN * 4);
  int*   bsum   = (int*)carve(128 * 4);
  int*   flag   = (int*)carve(256);
  float* dis    = (float*)carve((size_t)NN * 4);
  int2*  recs   = (int2*)carve((size_t)NE * 8);  // 25.6 MB
  f16*   W1t    = (f16*)carve((size_t)DHID * DIN * 2);
  f16*   W2t    = (f16*)carve((size_t)DOUT * DHID * 2);
  f16*   h_buf  = (f16*)carve((size_t)NN * DOUT * 2);
  f16*   z_a    = (f16*)carve((size_t)NN * DOUT * 2);
  f16*   z_b    = (f16*)carve((size_t)NN * DOUT * 2);
  if (off > ws_size) return; // ~67 MB needed

  detect_i64<<<1, 64, 0, stream>>>(ei, flag);
  zero_cnt<<<(NN + 255) / 256, 256, 0, stream>>>(cnt);
  count_deg<<<(NE / 4 + 255) / 256, 256, 0, stream>>>(ei, flag, cnt);
  scan1<<<(NN + 1023) / 1024, 1024, 0, stream>>>(cnt, rs, bsum);
  scan2<<<1, 64, 0, stream>>>(bsum, (NN + 1023) / 1024);
  scan3_and_dis<<<(NN + 255) / 256, 256, 0, stream>>>(rs, bsum, cursor, cnt, dis);
  fill_csr<<<(NE / 2 + 255) / 256, 256, 0, stream>>>(ei, flag, dis, cursor, recs);

  cvt_weights<<<(DIN * DHID + 255) / 256, 256, 0, stream>>>(W1, W2, W1t, W2t);
  mlp_mfma<<<(NN + 63) / 64, 256, 0, stream>>>(x, W1t, b1, W2t, b2, temp, h_buf, z_a);

  const f16* zc = z_a;
  f16* zn = z_b;
  for (int k = KPROP - 1; k >= 0; k--) {
    prop_horner<<<(NN + 3) / 4, 256, 0, stream>>>(zc, zn, h_buf, out, rs, cnt,
                                                  recs, dis, temp, k, k == 0);
    const f16* t2 = zn;
    zn = (f16*)zc;
    zc = t2;
  }
}

// Round 8
// 1017.052 us; speedup vs baseline: 2.0848x; 1.0133x over previous
//
#include <hip/hip_runtime.h>

#define NN 100000
#define NE 3200000
#define DIN 512
#define DHID 256
#define DOUT 64
#define KPROP 10
#define NPART 8
#define PSZ 12500   // nodes per dst-partition (8 x 12500 = 100000)

typedef _Float16 f16;
typedef _Float16 f16x8 __attribute__((ext_vector_type(8)));
typedef _Float16 f16x4 __attribute__((ext_vector_type(4)));
typedef float f32x4 __attribute__((ext_vector_type(4)));

// ---------------- edge-index layout probe (wave-parallel) ----------------
__global__ void detect_i64(const int* __restrict__ ei, int* __restrict__ flag) {
  int lane = threadIdx.x;
  int ok = 1;
  for (int i = lane; i < 512; i += 64)
    if (ei[2 * i + 1] != 0) ok = 0;
  ok = __all(ok);
  if (lane == 0) *flag = ok;
}

__global__ void zero_cnt(int* __restrict__ cnt) {
  int g = blockIdx.x * blockDim.x + threadIdx.x;
  if (g < NN) cnt[g] = 0;
}

// ---------------- degree count: XCD-routed ----------------
// Block b handles dst-partition (b&7) over edge chunk (b>>3). Consecutive
// blockIdx round-robin across XCDs (same mapping as T1's %8 swizzle), so all
// atomics to a given cnt line issue from ONE XCD -> line stays L2-resident.
// The 8x dst re-read streams through the shared 256MB L3 (cheap).
__global__ __launch_bounds__(256) void count_deg(
    const int* __restrict__ ei, const int* __restrict__ flag,
    int* __restrict__ cnt) {
  int p = blockIdx.x & 7;
  int chunk = blockIdx.x >> 3;
  int e0 = chunk * 1024 + threadIdx.x * 4;
  if (e0 >= NE) return;
  int is64 = *flag;
  int d0, d1, d2, d3;
  if (is64) {
    int4 a = *(const int4*)&ei[2 * (size_t)NE + 2 * (size_t)e0];
    int4 b = *(const int4*)&ei[2 * (size_t)NE + 2 * (size_t)e0 + 4];
    d0 = a.x; d1 = a.z; d2 = b.x; d3 = b.z;
  } else {
    int4 a = *(const int4*)&ei[(size_t)NE + e0];
    d0 = a.x; d1 = a.y; d2 = a.z; d3 = a.w;
  }
  int lo = p * PSZ, hi = lo + PSZ;
  if (d0 >= lo && d0 < hi) atomicAdd(&cnt[d0], 1);
  if (d1 >= lo && d1 < hi) atomicAdd(&cnt[d1], 1);
  if (d2 >= lo && d2 < hi) atomicAdd(&cnt[d2], 1);
  if (d3 >= lo && d3 < hi) atomicAdd(&cnt[d3], 1);
}

// ---------------- exclusive scan over cnt ----------------
__global__ void scan1(const int* __restrict__ cnt, int* __restrict__ rs,
                      int* __restrict__ bsum) {
  __shared__ int tmp[1024];
  int t = threadIdx.x;
  int g = blockIdx.x * 1024 + t;
  int v = (g < NN) ? cnt[g] : 0;
  tmp[t] = v;
  __syncthreads();
  for (int off = 1; off < 1024; off <<= 1) {
    int y = (t >= off) ? tmp[t - off] : 0;
    __syncthreads();
    tmp[t] += y;
    __syncthreads();
  }
  if (g < NN) rs[g] = tmp[t] - v;           // exclusive
  if (t == 1023) bsum[blockIdx.x] = tmp[t]; // block total
}

__global__ void scan2(int* __restrict__ bsum, int nb) {
  if (blockIdx.x == 0 && threadIdx.x == 0) {
    int s = 0;
    for (int i = 0; i < nb; i++) { int v = bsum[i]; bsum[i] = s; s += v; }
  }
}

__global__ void scan3_and_dis(int* __restrict__ rs, const int* __restrict__ bsum,
                              int* __restrict__ cursor, const int* __restrict__ cnt,
                              float* __restrict__ dis) {
  int g = blockIdx.x * blockDim.x + threadIdx.x;
  if (g < NN) {
    int v = rs[g] + bsum[g >> 10];
    rs[g] = v;
    cursor[g] = v;
    dis[g] = rsqrtf((float)(cnt[g] + 1)); // +1 self-loop
  }
}

// ---------------- CSR fill: XCD-routed {col, norm} records ----------------
// Same routing as count_deg: all 8B record stores to a given CSR line come
// from one XCD -> L2 accumulates the full 64B line before writeback (r7
// showed 7.8x write amplification without routing: 200MB for 25.6MB payload).
__global__ __launch_bounds__(256) void fill_csr(
    const int* __restrict__ ei, const int* __restrict__ flag,
    const float* __restrict__ dis, int* __restrict__ cursor,
    int2* __restrict__ recs) {
  int p = blockIdx.x & 7;
  int chunk = blockIdx.x >> 3;
  int e0 = chunk * 1024 + threadIdx.x * 4;
  if (e0 >= NE) return;
  int is64 = *flag;
  int d[4];
  if (is64) {
    int4 a = *(const int4*)&ei[2 * (size_t)NE + 2 * (size_t)e0];
    int4 b = *(const int4*)&ei[2 * (size_t)NE + 2 * (size_t)e0 + 4];
    d[0] = a.x; d[1] = a.z; d[2] = b.x; d[3] = b.z;
  } else {
    int4 a = *(const int4*)&ei[(size_t)NE + e0];
    d[0] = a.x; d[1] = a.y; d[2] = a.z; d[3] = a.w;
  }
  int lo = p * PSZ, hi = lo + PSZ;
  #pragma unroll
  for (int j = 0; j < 4; j++) {
    if (d[j] >= lo && d[j] < hi) {
      int s = is64 ? ei[2 * (size_t)(e0 + j)] : ei[e0 + j];
      int pos = atomicAdd(&cursor[d[j]], 1);
      recs[pos] = make_int2(s, __float_as_int(dis[s] * dis[d[j]]));
    }
  }
}

// ---------------- weight transpose + fp16 convert ----------------
__global__ void cvt_weights(const float* __restrict__ W1, const float* __restrict__ W2,
                            f16* __restrict__ W1t, f16* __restrict__ W2t) {
  int g = blockIdx.x * 256 + threadIdx.x;
  if (g < DIN * DHID) {
    int k = g >> 8, n = g & 255;
    W1t[(size_t)n * DIN + k] = (f16)W1[g];
  }
  if (g < DHID * DOUT) {
    int k = g >> 6, n = g & 63;
    W2t[(size_t)n * DHID + k] = (f16)W2[g];
  }
}

// ---------------- fused MLP via f16 MFMA (pipelined, union LDS) ----------
__global__ __launch_bounds__(256) void mlp_mfma(
    const float* __restrict__ x, const f16* __restrict__ W1t,
    const float* __restrict__ b1, const f16* __restrict__ W2t,
    const float* __restrict__ b2, const float* __restrict__ temp,
    f16* __restrict__ h, f16* __restrict__ z)
{
  __shared__ __align__(16) char smraw[2 * 64 * 136 * 2]; // 34816 B
  f16* xsb = (f16*)smraw;          // xs[buf][row][136]
  f16* h1s = (f16*)smraw;          // h1s[row][264] (aliases xs; disjoint lifetime)
  int t = threadIdx.x;
  int lane = t & 63;
  int w = t >> 6;
  int n0 = blockIdx.x * 64;
  int r15 = lane & 15;
  int g4 = lane >> 4;
  int nbase = w * 64;
  int srow = t >> 5, sc4 = t & 31;

  f32x4 acc[4][4];
  #pragma unroll
  for (int nt = 0; nt < 4; nt++) {
    float bv = b1[nbase + nt * 16 + r15];
    #pragma unroll
    for (int mt = 0; mt < 4; mt++) acc[mt][nt] = (f32x4){bv, bv, bv, bv};
  }

  float4 ld[8];
  #pragma unroll
  for (int it = 0; it < 8; it++) {
    int row = srow + it * 8;
    int gr = n0 + row;
    ld[it] = (gr < NN) ? *(const float4*)&x[(size_t)gr * DIN + sc4 * 4]
                       : make_float4(0.f, 0.f, 0.f, 0.f);
  }
  #pragma unroll
  for (int it = 0; it < 8; it++) {
    int row = srow + it * 8;
    f16x4 hv = { (f16)ld[it].x, (f16)ld[it].y, (f16)ld[it].z, (f16)ld[it].w };
    *(f16x4*)&xsb[row * 136 + sc4 * 4] = hv;
  }
  __syncthreads();

  for (int c = 0; c < 4; c++) {
    int cur = c & 1;
    if (c < 3) {
      #pragma unroll
      for (int it = 0; it < 8; it++) {
        int row = srow + it * 8;
        int gr = n0 + row;
        ld[it] = (gr < NN)
            ? *(const float4*)&x[(size_t)gr * DIN + (c + 1) * 128 + sc4 * 4]
            : make_float4(0.f, 0.f, 0.f, 0.f);
      }
    }
    int k0 = c * 128;
    const f16* xs = xsb + cur * 8704;
    #pragma unroll
    for (int ks = 0; ks < 4; ks++) {
      int kk = ks * 32 + g4 * 8;
      f16x8 a[4], b[4];
      #pragma unroll
      for (int mt = 0; mt < 4; mt++)
        a[mt] = *(const f16x8*)&xs[(mt * 16 + r15) * 136 + kk];
      #pragma unroll
      for (int nt = 0; nt < 4; nt++)
        b[nt] = *(const f16x8*)&W1t[(size_t)(nbase + nt * 16 + r15) * DIN + k0 + kk];
      #pragma unroll
      for (int mt = 0; mt < 4; mt++)
        #pragma unroll
        for (int nt = 0; nt < 4; nt++)
          acc[mt][nt] = __builtin_amdgcn_mfma_f32_16x16x32_f16(a[mt], b[nt], acc[mt][nt], 0, 0, 0);
    }
    if (c < 3) {
      #pragma unroll
      for (int it = 0; it < 8; it++) {
        int row = srow + it * 8;
        f16x4 hv = { (f16)ld[it].x, (f16)ld[it].y, (f16)ld[it].z, (f16)ld[it].w };
        *(f16x4*)&xsb[(cur ^ 1) * 8704 + row * 136 + sc4 * 4] = hv;
      }
    }
    __syncthreads();
  }

  #pragma unroll
  for (int mt = 0; mt < 4; mt++)
    #pragma unroll
    for (int nt = 0; nt < 4; nt++)
      #pragma unroll
      for (int r = 0; r < 4; r++) {
        float v = fmaxf(acc[mt][nt][r], 0.f);
        h1s[(mt * 16 + g4 * 4 + r) * 264 + nbase + nt * 16 + r15] = (f16)v;
      }
  __syncthreads();

  f32x4 acc2[4];
  #pragma unroll
  for (int nt = 0; nt < 4; nt++) {
    float bv = b2[nt * 16 + r15];
    acc2[nt] = (f32x4){bv, bv, bv, bv};
  }
  #pragma unroll
  for (int ks = 0; ks < 8; ks++) {
    int kk = ks * 32 + g4 * 8;
    f16x8 a2 = *(const f16x8*)&h1s[(w * 16 + r15) * 264 + kk];
    #pragma unroll
    for (int nt = 0; nt < 4; nt++) {
      f16x8 bf = *(const f16x8*)&W2t[(size_t)(nt * 16 + r15) * DHID + kk];
      acc2[nt] = __builtin_amdgcn_mfma_f32_16x16x32_f16(a2, bf, acc2[nt], 0, 0, 0);
    }
  }
  float tK = temp[KPROP];
  #pragma unroll
  for (int nt = 0; nt < 4; nt++)
    #pragma unroll
    for (int r = 0; r < 4; r++) {
      int node = n0 + w * 16 + g4 * 4 + r;
      if (node < NN) {
        int colv = nt * 16 + r15;
        float v = acc2[nt][r];
        h[(size_t)node * DOUT + colv] = (f16)v;
        z[(size_t)node * DOUT + colv] = (f16)(tK * v);
      }
    }
}

// ---------------- Horner propagation: z_new = temp[k]*h + A_hat z ----------
__global__ __launch_bounds__(256) void prop_horner(
    const f16* __restrict__ z, f16* __restrict__ zn, const f16* __restrict__ h,
    float* __restrict__ out, const int* __restrict__ rs, const int* __restrict__ cnt,
    const int2* __restrict__ recs, const float* __restrict__ dis,
    const float* __restrict__ temp, int kidx, int final_step)
{
  int w = blockIdx.x * 4 + (threadIdx.x >> 6);
  int lane = threadIdx.x & 63;
  if (w >= NN) return;
  int q = lane >> 3;
  int s8 = lane & 7;

  float acc[8];
  #pragma unroll
  for (int f = 0; f < 8; f++) acc[f] = 0.f;

  int beg = rs[w], n = cnt[w];
  const int2* rp = recs + beg;

  int e = 0;
  for (; e + 32 <= n; e += 32) {
    int2 r0 = rp[e + q];
    int2 r1 = rp[e + 8 + q];
    int2 r2 = rp[e + 16 + q];
    int2 r3 = rp[e + 24 + q];
    f16x8 g0 = *(const f16x8*)&z[(size_t)r0.x * DOUT + s8 * 8];
    f16x8 g1 = *(const f16x8*)&z[(size_t)r1.x * DOUT + s8 * 8];
    f16x8 g2 = *(const f16x8*)&z[(size_t)r2.x * DOUT + s8 * 8];
    f16x8 g3 = *(const f16x8*)&z[(size_t)r3.x * DOUT + s8 * 8];
    float w0 = __int_as_float(r0.y);
    float w1 = __int_as_float(r1.y);
    float w2 = __int_as_float(r2.y);
    float w3 = __int_as_float(r3.y);
    #pragma unroll
    for (int f = 0; f < 8; f++) acc[f] = fmaf(w0, (float)g0[f], acc[f]);
    #pragma unroll
    for (int f = 0; f < 8; f++) acc[f] = fmaf(w1, (float)g1[f], acc[f]);
    #pragma unroll
    for (int f = 0; f < 8; f++) acc[f] = fmaf(w2, (float)g2[f], acc[f]);
    #pragma unroll
    for (int f = 0; f < 8; f++) acc[f] = fmaf(w3, (float)g3[f], acc[f]);
  }
  for (; e + 8 <= n; e += 8) {
    int2 r0 = rp[e + q];
    f16x8 g0 = *(const f16x8*)&z[(size_t)r0.x * DOUT + s8 * 8];
    float w0 = __int_as_float(r0.y);
    #pragma unroll
    for (int f = 0; f < 8; f++) acc[f] = fmaf(w0, (float)g0[f], acc[f]);
  }
  if (e < n) {
    int rem = n - e;
    int qq = q < rem ? q : rem - 1;   // clamp; invalid slots get weight 0
    int2 r0 = rp[e + qq];
    f16x8 g0 = *(const f16x8*)&z[(size_t)r0.x * DOUT + s8 * 8];
    float w0 = (q < rem) ? __int_as_float(r0.y) : 0.f;
    #pragma unroll
    for (int f = 0; f < 8; f++) acc[f] = fmaf(w0, (float)g0[f], acc[f]);
  }

  #pragma unroll
  for (int f = 0; f < 8; f++) {
    acc[f] += __shfl_xor(acc[f], 8);
    acc[f] += __shfl_xor(acc[f], 16);
    acc[f] += __shfl_xor(acc[f], 32);
  }

  if (q == 0) {
    float dd = dis[w];
    float dd2 = dd * dd;              // self-loop norm
    float gk = temp[kidx];
    f16x8 zs = *(const f16x8*)&z[(size_t)w * DOUT + s8 * 8];
    f16x8 hs = *(const f16x8*)&h[(size_t)w * DOUT + s8 * 8];
    #pragma unroll
    for (int f = 0; f < 8; f++)
      acc[f] += dd2 * (float)zs[f] + gk * (float)hs[f];
    if (final_step) {
      float4 o0 = { acc[0], acc[1], acc[2], acc[3] };
      float4 o1 = { acc[4], acc[5], acc[6], acc[7] };
      *(float4*)&out[(size_t)w * DOUT + s8 * 8] = o0;
      *(float4*)&out[(size_t)w * DOUT + s8 * 8 + 4] = o1;
    } else {
      f16x8 o;
      #pragma unroll
      for (int f = 0; f < 8; f++) o[f] = (f16)acc[f];
      *(f16x8*)&zn[(size_t)w * DOUT + s8 * 8] = o;
    }
  }
}

// ---------------- launch ----------------
extern "C" void kernel_launch(void* const* d_in, const int* in_sizes, int n_in,
                              void* d_out, int out_size, void* d_ws, size_t ws_size,
                              hipStream_t stream) {
  const float* x    = (const float*)d_in[0];
  const int*   ei   = (const int*)d_in[1];
  const float* W1   = (const float*)d_in[2];
  const float* b1   = (const float*)d_in[3];
  const float* W2   = (const float*)d_in[4];
  const float* b2   = (const float*)d_in[5];
  const float* temp = (const float*)d_in[6];
  float* out = (float*)d_out;

  char* wsb = (char*)d_ws;
  size_t off = 0;
  auto carve = [&](size_t bytes) -> void* {
    void* p = wsb + off;
    off = (off + bytes + 255) & ~(size_t)255;
    return p;
  };
  int*   cnt    = (int*)carve((size_t)NN * 4);
  int*   rs     = (int*)carve((size_t)NN * 4);
  int*   cursor = (int*)carve((size_t)NN * 4);
  int*   bsum   = (int*)carve(128 * 4);
  int*   flag   = (int*)carve(256);
  float* dis    = (float*)carve((size_t)NN * 4);
  int2*  recs   = (int2*)carve((size_t)NE * 8);  // 25.6 MB
  f16*   W1t    = (f16*)carve((size_t)DHID * DIN * 2);
  f16*   W2t    = (f16*)carve((size_t)DOUT * DHID * 2);
  f16*   h_buf  = (f16*)carve((size_t)NN * DOUT * 2);
  f16*   z_a    = (f16*)carve((size_t)NN * DOUT * 2);
  f16*   z_b    = (f16*)carve((size_t)NN * DOUT * 2);
  if (off > ws_size) return; // ~67 MB needed

  int nchunks = NE / 1024;  // 3125 (exact)

  detect_i64<<<1, 64, 0, stream>>>(ei, flag);
  zero_cnt<<<(NN + 255) / 256, 256, 0, stream>>>(cnt);
  count_deg<<<nchunks * NPART, 256, 0, stream>>>(ei, flag, cnt);
  scan1<<<(NN + 1023) / 1024, 1024, 0, stream>>>(cnt, rs, bsum);
  scan2<<<1, 64, 0, stream>>>(bsum, (NN + 1023) / 1024);
  scan3_and_dis<<<(NN + 255) / 256, 256, 0, stream>>>(rs, bsum, cursor, cnt, dis);
  fill_csr<<<nchunks * NPART, 256, 0, stream>>>(ei, flag, dis, cursor, recs);

  cvt_weights<<<(DIN * DHID + 255) / 256, 256, 0, stream>>>(W1, W2, W1t, W2t);
  mlp_mfma<<<(NN + 63) / 64, 256, 0, stream>>>(x, W1t, b1, W2t, b2, temp, h_buf, z_a);

  const f16* zc = z_a;
  f16* zn = z_b;
  for (int k = KPROP - 1; k >= 0; k--) {
    prop_horner<<<(NN + 3) / 4, 256, 0, stream>>>(zc, zn, h_buf, out, rs, cnt,
                                                  recs, dis, temp, k, k == 0);
    const f16* t2 = zn;
    zn = (f16*)zc;
    zc = t2;
  }
}